// Round 5
// baseline (187.920 us; speedup 1.0000x reference)
//
#include <hip/hip_runtime.h>
#include <math.h>

namespace {

constexpr int E_  = 768;
constexpr int H_  = 12;
constexpr int DH_ = 64;
constexpr int T_  = 2048;
constexpr int B_  = 2;
constexpr int M_  = B_ * T_;  // 4096

typedef __attribute__((ext_vector_type(8))) short bf16x8;
typedef __attribute__((ext_vector_type(4))) float f32x4;

__device__ inline ushort f2bf(float f) {
  union { float f; unsigned u; } v; v.f = f;
  unsigned u = v.u + 0x7FFFu + ((v.u >> 16) & 1u);  // RNE
  return (ushort)(u >> 16);
}

// ---------------------------------------------------------------------------
// x f32 -> bf16, elementwise (8 per thread)
// ---------------------------------------------------------------------------
__global__ __launch_bounds__(256) void convert_x_k(
    const float* __restrict__ x, ushort* __restrict__ xb)
{
  const size_t i = ((size_t)blockIdx.x * 256 + threadIdx.x) * 8;
  float4 a = *(const float4*)(x + i);
  float4 b = *(const float4*)(x + i + 4);
  ushort o[8] = {f2bf(a.x), f2bf(a.y), f2bf(a.z), f2bf(a.w),
                 f2bf(b.x), f2bf(b.y), f2bf(b.z), f2bf(b.w)};
  *(bf16x8*)(xb + i) = *(bf16x8*)o;
}

// ---------------------------------------------------------------------------
// Weight transpose + convert: W [K][N] f32 -> Wt [N][K] bf16 (k-contiguous).
// ---------------------------------------------------------------------------
__global__ __launch_bounds__(256) void transpose_w_k(
    const float* __restrict__ Wq, const float* __restrict__ Wk,
    const float* __restrict__ Wv, const float* __restrict__ Wp,
    ushort* __restrict__ Wt, ushort* __restrict__ Wpt)
{
  __shared__ float tile[64][65];
  const int bid = blockIdx.x;
  const int tid = threadIdx.x;
  const int tr = tid >> 4, tc = tid & 15;

  const float* src; ushort* dst;
  int k0, n0, sN, dK;
  if (bid < 432) {
    const int mat = bid / 144, rem = bid % 144;
    const int h = rem / 12, ktile = rem % 12;
    const float* W = (mat == 0) ? Wq : (mat == 1) ? Wk : Wv;
    src = W + (size_t)h * E_ * DH_;
    dst = Wt + (size_t)(mat * H_ + h) * DH_ * E_;
    k0 = ktile * 64; n0 = 0; sN = DH_; dK = E_;
  } else {
    const int rem = bid - 432;
    src = Wp;
    dst = Wpt;
    k0 = (rem / 12) * 64; n0 = (rem % 12) * 64; sN = E_; dK = E_;
  }

#pragma unroll
  for (int rr = 0; rr < 64; rr += 16) {
    float4 v = *(const float4*)(src + (size_t)(k0 + tr + rr) * sN + n0 + tc * 4);
    tile[tr + rr][tc * 4 + 0] = v.x;
    tile[tr + rr][tc * 4 + 1] = v.y;
    tile[tr + rr][tc * 4 + 2] = v.z;
    tile[tr + rr][tc * 4 + 3] = v.w;
  }
  __syncthreads();
#pragma unroll
  for (int rr = 0; rr < 64; rr += 16) {
    const int n = tr + rr;
    ushort4 o;
    o.x = f2bf(tile[tc * 4 + 0][n]);
    o.y = f2bf(tile[tc * 4 + 1][n]);
    o.z = f2bf(tile[tc * 4 + 2][n]);
    o.w = f2bf(tile[tc * 4 + 3][n]);
    *(ushort4*)(dst + (size_t)(n0 + n) * dK + k0 + tc * 4) = o;
  }
}

// ---------------------------------------------------------------------------
// QKV MFMA GEMM. Q pre-scaled by 0.125*log2(e) (exp2-domain softmax).
// Q,K -> ws[(b*H+h)][t][64]; V -> TRANSPOSED vt_ws[(b*H+h)][d][t] via LDS bounce.
// ---------------------------------------------------------------------------
constexpr int GLD = 72;   // padded LDS row stride (bf16 elems)
constexpr int TDS = 136;  // V-transpose bounce row stride

__global__ __launch_bounds__(256) void qkv_mfma_k(
    const ushort* __restrict__ xb, const ushort* __restrict__ Wt,
    ushort* __restrict__ q_ws, ushort* __restrict__ k_ws, ushort* __restrict__ vt_ws)
{
  __shared__ __align__(16) ushort As[128 * GLD];  // [m][k]
  __shared__ __align__(16) ushort Bs[64 * GLD];   // [n][k]

  const int bx  = blockIdx.x;
  const int m0  = blockIdx.y * 128;
  const int mat = bx / H_;
  const int h   = bx - mat * H_;
  const ushort* Wh = Wt + (size_t)bx * DH_ * E_;

  const int tid  = threadIdx.x;
  const int w    = tid >> 6, l = tid & 63;
  const int lrow = l & 15, lk = l >> 4;

  f32x4 acc[2][4] = {};

  for (int k0 = 0; k0 < E_; k0 += 64) {
#pragma unroll
    for (int it = 0; it < 4; ++it) {
      const int c = tid + it * 256;
      const int r = c >> 3, sub = c & 7;
      *(bf16x8*)&As[r * GLD + sub * 8] =
          *(const bf16x8*)(xb + (size_t)(m0 + r) * E_ + k0 + sub * 8);
    }
#pragma unroll
    for (int it = 0; it < 2; ++it) {
      const int c = tid + it * 256;
      const int r = c >> 3, sub = c & 7;
      *(bf16x8*)&Bs[r * GLD + sub * 8] =
          *(const bf16x8*)(Wh + (size_t)r * E_ + k0 + sub * 8);
    }
    __syncthreads();

#pragma unroll
    for (int kk = 0; kk < 2; ++kk) {
      const bf16x8 a0 = *(const bf16x8*)&As[(w * 32 + lrow) * GLD + kk * 32 + lk * 8];
      const bf16x8 a1 = *(const bf16x8*)&As[(w * 32 + 16 + lrow) * GLD + kk * 32 + lk * 8];
#pragma unroll
      for (int ni = 0; ni < 4; ++ni) {
        const bf16x8 b = *(const bf16x8*)&Bs[(ni * 16 + lrow) * GLD + kk * 32 + lk * 8];
        acc[0][ni] = __builtin_amdgcn_mfma_f32_16x16x32_bf16(a0, b, acc[0][ni], 0, 0, 0);
        acc[1][ni] = __builtin_amdgcn_mfma_f32_16x16x32_bf16(a1, b, acc[1][ni], 0, 0, 0);
      }
    }
    __syncthreads();
  }

  const int b  = m0 / T_;
  const int bh = b * H_ + h;

  if (mat != 2) {
    const float qs = (mat == 0) ? 0.18033688f : 1.0f;  // 1/8 * log2(e)
    ushort* outw = (mat == 0) ? q_ws : k_ws;
#pragma unroll
    for (int mi = 0; mi < 2; ++mi)
#pragma unroll
      for (int i = 0; i < 4; ++i) {
        const int t = m0 + w * 32 + mi * 16 + lk * 4 + i - b * T_;
        ushort* orow = outw + ((size_t)bh * T_ + t) * DH_;
#pragma unroll
        for (int ni = 0; ni < 4; ++ni)
          orow[ni * 16 + lrow] = f2bf(acc[mi][ni][i] * qs);
      }
  } else {
    // V: transpose 128x64 tile through LDS -> vt_ws[bh][d][t]
    ushort* Td = (ushort*)As;  // [64][TDS]
#pragma unroll
    for (int mi = 0; mi < 2; ++mi)
#pragma unroll
      for (int i = 0; i < 4; ++i) {
        const int tl = w * 32 + mi * 16 + lk * 4 + i;
#pragma unroll
        for (int ni = 0; ni < 4; ++ni)
          Td[(ni * 16 + lrow) * TDS + tl] = f2bf(acc[mi][ni][i]);
      }
    __syncthreads();
    const int t0 = m0 - b * T_;
#pragma unroll
    for (int it = 0; it < 4; ++it) {
      const int c = tid + it * 256;
      const int d = c >> 4, sub = c & 15;
      *(bf16x8*)(vt_ws + ((size_t)bh * DH_ + d) * T_ + t0 + sub * 8) =
          *(const bf16x8*)&Td[d * TDS + sub * 8];
    }
  }
}

// ---------------------------------------------------------------------------
// Causal flash attention: barrier-free k-loop, K/V fragments direct from
// L1/L2 (64B-coalesced per instruction; K+V per head = 512KB, 3 heads/XCD
// = 1.5MB < 4MB XCD-L2). Only P bounces through per-wave XOR-swizzled LDS.
// Defer-max (THR=8, exp2 domain) skips O-rescale on most tiles.
// grid (x = bh = 24 -> fixed XCD per head, y: qt = 31-y, long first).
// ---------------------------------------------------------------------------
__global__ __launch_bounds__(256, 3) void attn_mfma_k(
    const ushort* __restrict__ q_ws, const ushort* __restrict__ k_ws,
    const ushort* __restrict__ vt_ws, ushort* __restrict__ o_ws)
{
  __shared__ __align__(16) ushort Pl[4][16 * 64];  // per-wave P [q][s], swizzled

  const int qt = 31 - (int)blockIdx.y;
  const int bh = blockIdx.x;
  const int q0 = qt * 64;
  const ushort* Qb  = q_ws + (size_t)bh * T_ * DH_;
  const ushort* Kb  = k_ws + (size_t)bh * T_ * DH_;
  const ushort* VTb = vt_ws + (size_t)bh * DH_ * T_;

  const int tid  = threadIdx.x;
  const int w    = tid >> 6;
  const int l    = tid & 63;
  const int lrow = l & 15;
  const int lk   = l >> 4;
  const int r7   = lrow & 7;

  // Q fragment (B-operand of swapped QK^T)
  const ushort* Qrow = Qb + (size_t)(q0 + w * 16 + lrow) * DH_;
  const bf16x8 qa0 = *(const bf16x8*)(Qrow + lk * 8);
  const bf16x8 qa1 = *(const bf16x8*)(Qrow + lk * 8 + 32);
  const int qglob = q0 + w * 16 + lrow;

  float m_r = -INFINITY, l_r = 0.f;
  f32x4 oc[4] = {};

  ushort* Pw = &Pl[w][0];
  // swizzled P read offsets (elems): chunk ^ r7 within 128B row
  const int rd0 = lrow * 64 + ((lk ^ r7) * 8);
  const int rd1 = lrow * 64 + (((lk + 4) ^ r7) * 8);
  // swizzled P write offset (bytes): 8B granule inside 16B chunk
  const int wrbase = lrow * 128 + (lk & 1) * 8;
  const int wrchunk = (lk >> 1);  // + ct*2, then ^ r7

  for (int kt = 0; kt <= qt; ++kt) {
    const int s0 = kt * 64;

    // K and V^T fragments direct from global (16 rows x 64B per instr)
    bf16x8 kb[8], vb[8];
#pragma unroll
    for (int ct = 0; ct < 4; ++ct) {
      const ushort* kr = Kb + (size_t)(s0 + ct * 16 + lrow) * DH_ + lk * 8;
      kb[2 * ct]     = *(const bf16x8*)(kr);
      kb[2 * ct + 1] = *(const bf16x8*)(kr + 32);
      const ushort* vr = VTb + (size_t)(ct * 16 + lrow) * T_ + s0 + lk * 8;
      vb[2 * ct]     = *(const bf16x8*)(vr);
      vb[2 * ct + 1] = *(const bf16x8*)(vr + 32);
    }

    // S^T = K Q^T : lane holds s = s0+ct*16+lk*4+i, q = lrow
    f32x4 st[4];
#pragma unroll
    for (int ct = 0; ct < 4; ++ct) {
      f32x4 z = {0.f, 0.f, 0.f, 0.f};
      z = __builtin_amdgcn_mfma_f32_16x16x32_bf16(kb[2 * ct], qa0, z, 0, 0, 0);
      st[ct] = __builtin_amdgcn_mfma_f32_16x16x32_bf16(kb[2 * ct + 1], qa1, z, 0, 0, 0);
    }

    // causal mask: only the diagonal tile (uniform branch)
    if (kt == qt) {
#pragma unroll
      for (int ct = 0; ct < 4; ++ct)
#pragma unroll
        for (int i = 0; i < 4; ++i)
          if (s0 + ct * 16 + lk * 4 + i > qglob) st[ct][i] = -INFINITY;
    }

    // row max (16 in-lane + 2 shuffles)
    float mx = st[0][0];
#pragma unroll
    for (int ct = 0; ct < 4; ++ct)
#pragma unroll
      for (int i = 0; i < 4; ++i) mx = fmaxf(mx, st[ct][i]);
    mx = fmaxf(mx, __shfl_xor(mx, 16));
    mx = fmaxf(mx, __shfl_xor(mx, 32));

    // defer-max: rescale only if some row grew by > 8 (exp2 domain)
    if (__any(mx > m_r + 8.f)) {
      const float mn   = fmaxf(m_r, mx);
      const float corr = exp2f(m_r - mn);  // first tile: exp2(-inf)=0
      m_r = mn;
      l_r *= corr;
#pragma unroll
      for (int i = 0; i < 4; ++i) {
        const float cr = __shfl(corr, lk * 4 + i);
#pragma unroll
        for (int ct = 0; ct < 4; ++ct) oc[ct][i] *= cr;
      }
    }

    float rs = 0.f;
#pragma unroll
    for (int ct = 0; ct < 4; ++ct)
#pragma unroll
      for (int i = 0; i < 4; ++i) {
        const float p = exp2f(st[ct][i] - m_r);
        st[ct][i] = p;
        rs += p;
      }
    rs += __shfl_xor(rs, 16);
    rs += __shfl_xor(rs, 32);
    l_r += rs;

    // P^T -> per-wave LDS (packed bf16, swizzled 8B stores; no barrier)
#pragma unroll
    for (int ct = 0; ct < 4; ++ct) {
      unsigned lo, hi;
      asm("v_cvt_pk_bf16_f32 %0, %1, %2" : "=v"(lo) : "v"(st[ct][0]), "v"(st[ct][1]));
      asm("v_cvt_pk_bf16_f32 %0, %1, %2" : "=v"(hi) : "v"(st[ct][2]), "v"(st[ct][3]));
      uint2 pk; pk.x = lo; pk.y = hi;
      const int ch = ((ct * 2 + wrchunk) ^ r7);
      *(uint2*)((char*)Pw + wrbase + ch * 16) = pk;
    }

    const bf16x8 pa0 = *(const bf16x8*)(Pw + rd0);
    const bf16x8 pa1 = *(const bf16x8*)(Pw + rd1);

    // O += P V
#pragma unroll
    for (int ct = 0; ct < 4; ++ct) {
      oc[ct] = __builtin_amdgcn_mfma_f32_16x16x32_bf16(pa0, vb[2 * ct], oc[ct], 0, 0, 0);
      oc[ct] = __builtin_amdgcn_mfma_f32_16x16x32_bf16(pa1, vb[2 * ct + 1], oc[ct], 0, 0, 0);
    }
  }

  // epilogue: normalize (broadcast l), write concat-heads bf16
  const int bb = bh / H_, hh = bh - (bh / H_) * H_;
#pragma unroll
  for (int i = 0; i < 4; ++i) {
    const float lv  = __shfl(l_r, lk * 4 + i);
    const float inv = 1.0f / lv;
    const int t = q0 + w * 16 + lk * 4 + i;
    ushort* orow = o_ws + ((size_t)bb * T_ + t) * E_ + hh * DH_;
#pragma unroll
    for (int ct = 0; ct < 4; ++ct)
      orow[ct * 16 + lrow] = f2bf(oc[ct][i] * inv);
  }
}

// ---------------------------------------------------------------------------
// Out-proj MFMA GEMM: out = ob @ Wp + bp  (bf16 in, f32 out)
// ---------------------------------------------------------------------------
__global__ __launch_bounds__(256) void proj_mfma_k(
    const ushort* __restrict__ ob, const ushort* __restrict__ Wpt,
    const float* __restrict__ bp, float* __restrict__ out)
{
  __shared__ __align__(16) ushort As[128 * GLD];
  __shared__ __align__(16) ushort Bs[64 * GLD];

  const int n0 = blockIdx.x * 64;
  const int m0 = blockIdx.y * 128;

  const int tid  = threadIdx.x;
  const int w    = tid >> 6, l = tid & 63;
  const int lrow = l & 15, lk = l >> 4;

  f32x4 acc[2][4] = {};

  for (int k0 = 0; k0 < E_; k0 += 64) {
#pragma unroll
    for (int it = 0; it < 4; ++it) {
      const int c = tid + it * 256;
      const int r = c >> 3, sub = c & 7;
      *(bf16x8*)&As[r * GLD + sub * 8] =
          *(const bf16x8*)(ob + (size_t)(m0 + r) * E_ + k0 + sub * 8);
    }
#pragma unroll
    for (int it = 0; it < 2; ++it) {
      const int c = tid + it * 256;
      const int r = c >> 3, sub = c & 7;
      *(bf16x8*)&Bs[r * GLD + sub * 8] =
          *(const bf16x8*)(Wpt + (size_t)(n0 + r) * E_ + k0 + sub * 8);
    }
    __syncthreads();

#pragma unroll
    for (int kk = 0; kk < 2; ++kk) {
      const bf16x8 a0 = *(const bf16x8*)&As[(w * 32 + lrow) * GLD + kk * 32 + lk * 8];
      const bf16x8 a1 = *(const bf16x8*)&As[(w * 32 + 16 + lrow) * GLD + kk * 32 + lk * 8];
#pragma unroll
      for (int ni = 0; ni < 4; ++ni) {
        const bf16x8 b = *(const bf16x8*)&Bs[(ni * 16 + lrow) * GLD + kk * 32 + lk * 8];
        acc[0][ni] = __builtin_amdgcn_mfma_f32_16x16x32_bf16(a0, b, acc[0][ni], 0, 0, 0);
        acc[1][ni] = __builtin_amdgcn_mfma_f32_16x16x32_bf16(a1, b, acc[1][ni], 0, 0, 0);
      }
    }
    __syncthreads();
  }

  float bias[4];
#pragma unroll
  for (int ni = 0; ni < 4; ++ni) bias[ni] = bp[n0 + ni * 16 + lrow];

#pragma unroll
  for (int mi = 0; mi < 2; ++mi)
#pragma unroll
    for (int i = 0; i < 4; ++i) {
      const int m = m0 + w * 32 + mi * 16 + lk * 4 + i;
      float* orow = out + (size_t)m * E_ + n0;
#pragma unroll
      for (int ni = 0; ni < 4; ++ni)
        orow[ni * 16 + lrow] = acc[mi][ni][i] + bias[ni];
    }
}

}  // namespace

extern "C" void kernel_launch(void* const* d_in, const int* in_sizes, int n_in,
                              void* d_out, int out_size, void* d_ws, size_t ws_size,
                              hipStream_t stream) {
  const float* x  = (const float*)d_in[0];
  const float* Wq = (const float*)d_in[1];
  const float* Wk = (const float*)d_in[2];
  const float* Wv = (const float*)d_in[3];
  const float* Wp = (const float*)d_in[4];
  const float* bp = (const float*)d_in[5];
  float* out = (float*)d_out;

  const size_t nx  = (size_t)M_ * E_;
  const size_t nwt = (size_t)3 * H_ * DH_ * E_;
  const size_t nwp = (size_t)E_ * E_;
  const size_t per = (size_t)B_ * H_ * T_ * DH_;

  ushort* xb    = (ushort*)d_ws;
  ushort* Wt    = xb + nx;
  ushort* Wpt   = Wt + nwt;
  ushort* q_ws  = Wpt + nwp;
  ushort* k_ws  = q_ws + per;
  ushort* vt_ws = k_ws + per;   // [bh][d][t] transposed V
  ushort* o_b   = vt_ws + per;

  convert_x_k<<<dim3((int)(nx / (256 * 8))), 256, 0, stream>>>(x, xb);
  transpose_w_k<<<dim3(576), 256, 0, stream>>>(Wq, Wk, Wv, Wp, Wt, Wpt);
  qkv_mfma_k<<<dim3(36, 32), 256, 0, stream>>>(xb, Wt, q_ws, k_ws, vt_ws);
  attn_mfma_k<<<dim3(24, 32), 256, 0, stream>>>(q_ws, k_ws, vt_ws, o_b);
  proj_mfma_k<<<dim3(12, 32), 256, 0, stream>>>(o_b, Wpt, bp, out);
}

// Round 6
// 115.370 us; speedup vs baseline: 1.6288x; 1.6288x over previous
//
#include <hip/hip_runtime.h>
#include <math.h>

namespace {

constexpr int E_  = 768;
constexpr int H_  = 12;
constexpr int DH_ = 64;
constexpr int T_  = 2048;
constexpr int B_  = 2;
constexpr int M_  = B_ * T_;  // 4096

typedef __attribute__((ext_vector_type(8))) short bf16x8;
typedef __attribute__((ext_vector_type(4))) float f32x4;

__device__ inline ushort f2bf(float f) {
  union { float f; unsigned u; } v; v.f = f;
  unsigned u = v.u + 0x7FFFu + ((v.u >> 16) & 1u);  // RNE
  return (ushort)(u >> 16);
}

// ---------------------------------------------------------------------------
// x f32 -> bf16, elementwise (8 per thread)
// ---------------------------------------------------------------------------
__global__ __launch_bounds__(256) void convert_x_k(
    const float* __restrict__ x, ushort* __restrict__ xb)
{
  const size_t i = ((size_t)blockIdx.x * 256 + threadIdx.x) * 8;
  float4 a = *(const float4*)(x + i);
  float4 b = *(const float4*)(x + i + 4);
  ushort o[8] = {f2bf(a.x), f2bf(a.y), f2bf(a.z), f2bf(a.w),
                 f2bf(b.x), f2bf(b.y), f2bf(b.z), f2bf(b.w)};
  *(bf16x8*)(xb + i) = *(bf16x8*)o;
}

// ---------------------------------------------------------------------------
// Weight transpose + convert: W [K][N] f32 -> Wt [N][K] bf16 (k-contiguous).
// ---------------------------------------------------------------------------
__global__ __launch_bounds__(256) void transpose_w_k(
    const float* __restrict__ Wq, const float* __restrict__ Wk,
    const float* __restrict__ Wv, const float* __restrict__ Wp,
    ushort* __restrict__ Wt, ushort* __restrict__ Wpt)
{
  __shared__ float tile[64][65];
  const int bid = blockIdx.x;
  const int tid = threadIdx.x;
  const int tr = tid >> 4, tc = tid & 15;

  const float* src; ushort* dst;
  int k0, n0, sN, dK;
  if (bid < 432) {
    const int mat = bid / 144, rem = bid % 144;
    const int h = rem / 12, ktile = rem % 12;
    const float* W = (mat == 0) ? Wq : (mat == 1) ? Wk : Wv;
    src = W + (size_t)h * E_ * DH_;
    dst = Wt + (size_t)(mat * H_ + h) * DH_ * E_;
    k0 = ktile * 64; n0 = 0; sN = DH_; dK = E_;
  } else {
    const int rem = bid - 432;
    src = Wp;
    dst = Wpt;
    k0 = (rem / 12) * 64; n0 = (rem % 12) * 64; sN = E_; dK = E_;
  }

#pragma unroll
  for (int rr = 0; rr < 64; rr += 16) {
    float4 v = *(const float4*)(src + (size_t)(k0 + tr + rr) * sN + n0 + tc * 4);
    tile[tr + rr][tc * 4 + 0] = v.x;
    tile[tr + rr][tc * 4 + 1] = v.y;
    tile[tr + rr][tc * 4 + 2] = v.z;
    tile[tr + rr][tc * 4 + 3] = v.w;
  }
  __syncthreads();
#pragma unroll
  for (int rr = 0; rr < 64; rr += 16) {
    const int n = tr + rr;
    ushort4 o;
    o.x = f2bf(tile[tc * 4 + 0][n]);
    o.y = f2bf(tile[tc * 4 + 1][n]);
    o.z = f2bf(tile[tc * 4 + 2][n]);
    o.w = f2bf(tile[tc * 4 + 3][n]);
    *(ushort4*)(dst + (size_t)(n0 + n) * dK + k0 + tc * 4) = o;
  }
}

// ---------------------------------------------------------------------------
// QKV MFMA GEMM. Q pre-scaled by 0.125*log2(e) (exp2-domain softmax).
// Q,K -> ws[(b*H+h)][t][64]; V -> TRANSPOSED vt_ws[(b*H+h)][d][t] via LDS bounce.
// ---------------------------------------------------------------------------
constexpr int GLD = 72;   // padded LDS row stride (bf16 elems)
constexpr int TDS = 136;  // V-transpose bounce row stride

__global__ __launch_bounds__(256) void qkv_mfma_k(
    const ushort* __restrict__ xb, const ushort* __restrict__ Wt,
    ushort* __restrict__ q_ws, ushort* __restrict__ k_ws, ushort* __restrict__ vt_ws)
{
  __shared__ __align__(16) ushort As[128 * GLD];  // [m][k]
  __shared__ __align__(16) ushort Bs[64 * GLD];   // [n][k]

  const int bx  = blockIdx.x;
  const int m0  = blockIdx.y * 128;
  const int mat = bx / H_;
  const int h   = bx - mat * H_;
  const ushort* Wh = Wt + (size_t)bx * DH_ * E_;

  const int tid  = threadIdx.x;
  const int w    = tid >> 6, l = tid & 63;
  const int lrow = l & 15, lk = l >> 4;

  f32x4 acc[2][4] = {};

  for (int k0 = 0; k0 < E_; k0 += 64) {
#pragma unroll
    for (int it = 0; it < 4; ++it) {
      const int c = tid + it * 256;
      const int r = c >> 3, sub = c & 7;
      *(bf16x8*)&As[r * GLD + sub * 8] =
          *(const bf16x8*)(xb + (size_t)(m0 + r) * E_ + k0 + sub * 8);
    }
#pragma unroll
    for (int it = 0; it < 2; ++it) {
      const int c = tid + it * 256;
      const int r = c >> 3, sub = c & 7;
      *(bf16x8*)&Bs[r * GLD + sub * 8] =
          *(const bf16x8*)(Wh + (size_t)r * E_ + k0 + sub * 8);
    }
    __syncthreads();

#pragma unroll
    for (int kk = 0; kk < 2; ++kk) {
      const bf16x8 a0 = *(const bf16x8*)&As[(w * 32 + lrow) * GLD + kk * 32 + lk * 8];
      const bf16x8 a1 = *(const bf16x8*)&As[(w * 32 + 16 + lrow) * GLD + kk * 32 + lk * 8];
#pragma unroll
      for (int ni = 0; ni < 4; ++ni) {
        const bf16x8 b = *(const bf16x8*)&Bs[(ni * 16 + lrow) * GLD + kk * 32 + lk * 8];
        acc[0][ni] = __builtin_amdgcn_mfma_f32_16x16x32_bf16(a0, b, acc[0][ni], 0, 0, 0);
        acc[1][ni] = __builtin_amdgcn_mfma_f32_16x16x32_bf16(a1, b, acc[1][ni], 0, 0, 0);
      }
    }
    __syncthreads();
  }

  const int b  = m0 / T_;
  const int bh = b * H_ + h;

  if (mat != 2) {
    const float qs = (mat == 0) ? 0.18033688f : 1.0f;  // 1/8 * log2(e)
    ushort* outw = (mat == 0) ? q_ws : k_ws;
#pragma unroll
    for (int mi = 0; mi < 2; ++mi)
#pragma unroll
      for (int i = 0; i < 4; ++i) {
        const int t = m0 + w * 32 + mi * 16 + lk * 4 + i - b * T_;
        ushort* orow = outw + ((size_t)bh * T_ + t) * DH_;
#pragma unroll
        for (int ni = 0; ni < 4; ++ni)
          orow[ni * 16 + lrow] = f2bf(acc[mi][ni][i] * qs);
      }
  } else {
    // V: transpose 128x64 tile through LDS -> vt_ws[bh][d][t]
    ushort* Td = (ushort*)As;  // [64][TDS]
#pragma unroll
    for (int mi = 0; mi < 2; ++mi)
#pragma unroll
      for (int i = 0; i < 4; ++i) {
        const int tl = w * 32 + mi * 16 + lk * 4 + i;
#pragma unroll
        for (int ni = 0; ni < 4; ++ni)
          Td[(ni * 16 + lrow) * TDS + tl] = f2bf(acc[mi][ni][i]);
      }
    __syncthreads();
    const int t0 = m0 - b * T_;
#pragma unroll
    for (int it = 0; it < 4; ++it) {
      const int c = tid + it * 256;
      const int d = c >> 4, sub = c & 15;
      *(bf16x8*)(vt_ws + ((size_t)bh * DH_ + d) * T_ + t0 + sub * 8) =
          *(const bf16x8*)&Td[d * TDS + sub * 8];
    }
  }
}

// ---------------------------------------------------------------------------
// Causal flash attention. R4 cooperative-LDS structure + R5 refinements:
//  - K/V tiles in XOR-swizzled LDS (128B rows, chunk^=row&7): conflict-free
//    b128 reads, no padding.
//  - Double-buffered K/V -> ONE barrier per k-tile.
//  - Per-wave swizzled P bounce (no barrier), defer-max, exp2 domain,
//    diagonal-only masking.
// grid (x = bh = 24, y: qt = 31-y, long blocks first).
// ---------------------------------------------------------------------------
__global__ __launch_bounds__(256) void attn_mfma_k(
    const ushort* __restrict__ q_ws, const ushort* __restrict__ k_ws,
    const ushort* __restrict__ vt_ws, ushort* __restrict__ o_ws)
{
  __shared__ __align__(16) ushort Ks[2][64 * 64];  // K tile [s][d], swizzled
  __shared__ __align__(16) ushort Vt[2][64 * 64];  // V^T tile [d][s], swizzled
  __shared__ __align__(16) ushort Pl[4][16 * 64];  // per-wave P [q][s], swizzled

  const int qt = 31 - (int)blockIdx.y;
  const int bh = blockIdx.x;
  const int q0 = qt * 64;
  const ushort* Qb  = q_ws + (size_t)bh * T_ * DH_;
  const ushort* Kb  = k_ws + (size_t)bh * T_ * DH_;
  const ushort* VTb = vt_ws + (size_t)bh * DH_ * T_;

  const int tid  = threadIdx.x;
  const int w    = tid >> 6;
  const int l    = tid & 63;
  const int lrow = l & 15;
  const int lk   = l >> 4;
  const int r7   = lrow & 7;
  const int rr   = tid >> 3;    // staging row 0..31 (row rr and rr+32)
  const int sub  = tid & 7;     // staging 16B chunk
  const int swc  = sub ^ (rr & 7);  // swizzled chunk (same for rr and rr+32)

  // staging LDS offsets (elems)
  const int st0 = rr * 64 + swc * 8;
  const int st1 = (rr + 32) * 64 + swc * 8;

  // fragment read offsets (elems), row = ct*16+lrow, chunks lk and lk+4
  int kof0[4], kof1[4];
#pragma unroll
  for (int ct = 0; ct < 4; ++ct) {
    kof0[ct] = (ct * 16 + lrow) * 64 + ((lk ^ r7) * 8);
    kof1[ct] = (ct * 16 + lrow) * 64 + (((lk + 4) ^ r7) * 8);
  }

  // Q fragment (B-operand of swapped QK^T)
  const ushort* Qrow = Qb + (size_t)(q0 + w * 16 + lrow) * DH_;
  const bf16x8 qa0 = *(const bf16x8*)(Qrow + lk * 8);
  const bf16x8 qa1 = *(const bf16x8*)(Qrow + lk * 8 + 32);
  const int qglob = q0 + w * 16 + lrow;

  float m_r = -INFINITY, l_r = 0.f;
  f32x4 oc[4] = {};

  ushort* Pw = &Pl[w][0];
  const int rd0 = lrow * 64 + ((lk ^ r7) * 8);
  const int rd1 = lrow * 64 + (((lk + 4) ^ r7) * 8);
  const int wrbase  = lrow * 128 + (lk & 1) * 8;  // bytes
  const int wrchunk = (lk >> 1);

  // prologue: tile 0 -> regs -> buf 0
  bf16x8 kp0 = *(const bf16x8*)(Kb + (size_t)rr * DH_ + sub * 8);
  bf16x8 kp1 = *(const bf16x8*)(Kb + (size_t)(rr + 32) * DH_ + sub * 8);
  bf16x8 vp0 = *(const bf16x8*)(VTb + (size_t)rr * T_ + sub * 8);
  bf16x8 vp1 = *(const bf16x8*)(VTb + (size_t)(rr + 32) * T_ + sub * 8);
  *(bf16x8*)&Ks[0][st0] = kp0;
  *(bf16x8*)&Ks[0][st1] = kp1;
  *(bf16x8*)&Vt[0][st0] = vp0;
  *(bf16x8*)&Vt[0][st1] = vp1;
  __syncthreads();

  for (int kt = 0; kt <= qt; ++kt) {
    const int s0  = kt * 64;
    const int cur = kt & 1;

    // issue next tile's global loads early (latency hides under compute)
    if (kt < qt) {
      const int sn = s0 + 64;
      kp0 = *(const bf16x8*)(Kb + (size_t)(sn + rr) * DH_ + sub * 8);
      kp1 = *(const bf16x8*)(Kb + (size_t)(sn + rr + 32) * DH_ + sub * 8);
      vp0 = *(const bf16x8*)(VTb + (size_t)rr * T_ + sn + sub * 8);
      vp1 = *(const bf16x8*)(VTb + (size_t)(rr + 32) * T_ + sn + sub * 8);
    }

    // S^T = K Q^T : lane holds s = s0+ct*16+lk*4+i, q = lrow
    f32x4 st[4];
#pragma unroll
    for (int ct = 0; ct < 4; ++ct) {
      const bf16x8 kb0 = *(const bf16x8*)&Ks[cur][kof0[ct]];
      const bf16x8 kb1 = *(const bf16x8*)&Ks[cur][kof1[ct]];
      f32x4 z = {0.f, 0.f, 0.f, 0.f};
      z = __builtin_amdgcn_mfma_f32_16x16x32_bf16(kb0, qa0, z, 0, 0, 0);
      st[ct] = __builtin_amdgcn_mfma_f32_16x16x32_bf16(kb1, qa1, z, 0, 0, 0);
    }

    // causal mask: diagonal tile only (uniform branch)
    if (kt == qt) {
#pragma unroll
      for (int ct = 0; ct < 4; ++ct)
#pragma unroll
        for (int i = 0; i < 4; ++i)
          if (s0 + ct * 16 + lk * 4 + i > qglob) st[ct][i] = -INFINITY;
    }

    // row max (16 in-lane + 2 shuffles across the lrow-sharing lanes)
    float mx = st[0][0];
#pragma unroll
    for (int ct = 0; ct < 4; ++ct)
#pragma unroll
      for (int i = 0; i < 4; ++i) mx = fmaxf(mx, st[ct][i]);
    mx = fmaxf(mx, __shfl_xor(mx, 16));
    mx = fmaxf(mx, __shfl_xor(mx, 32));

    // defer-max: rescale only if some row grew by > 8 (exp2 domain)
    if (__any(mx > m_r + 8.f)) {
      const float mn   = fmaxf(m_r, mx);
      const float corr = exp2f(m_r - mn);  // first tile: exp2(-inf)=0
      m_r = mn;
      l_r *= corr;
#pragma unroll
      for (int i = 0; i < 4; ++i) {
        const float cr = __shfl(corr, lk * 4 + i);
#pragma unroll
        for (int ct = 0; ct < 4; ++ct) oc[ct][i] *= cr;
      }
    }

    float rs = 0.f;
#pragma unroll
    for (int ct = 0; ct < 4; ++ct)
#pragma unroll
      for (int i = 0; i < 4; ++i) {
        const float p = exp2f(st[ct][i] - m_r);
        st[ct][i] = p;
        rs += p;
      }
    rs += __shfl_xor(rs, 16);
    rs += __shfl_xor(rs, 32);
    l_r += rs;

    // P^T -> per-wave LDS (packed bf16, swizzled 8B stores; no barrier)
#pragma unroll
    for (int ct = 0; ct < 4; ++ct) {
      unsigned lo, hi;
      asm("v_cvt_pk_bf16_f32 %0, %1, %2" : "=v"(lo) : "v"(st[ct][0]), "v"(st[ct][1]));
      asm("v_cvt_pk_bf16_f32 %0, %1, %2" : "=v"(hi) : "v"(st[ct][2]), "v"(st[ct][3]));
      uint2 pk; pk.x = lo; pk.y = hi;
      const int ch = ((ct * 2 + wrchunk) ^ r7);
      *(uint2*)((char*)Pw + wrbase + ch * 16) = pk;
    }

    const bf16x8 pa0 = *(const bf16x8*)(Pw + rd0);
    const bf16x8 pa1 = *(const bf16x8*)(Pw + rd1);

    // O += P V
#pragma unroll
    for (int ct = 0; ct < 4; ++ct) {
      const bf16x8 vb0 = *(const bf16x8*)&Vt[cur][kof0[ct]];
      const bf16x8 vb1 = *(const bf16x8*)&Vt[cur][kof1[ct]];
      oc[ct] = __builtin_amdgcn_mfma_f32_16x16x32_bf16(pa0, vb0, oc[ct], 0, 0, 0);
      oc[ct] = __builtin_amdgcn_mfma_f32_16x16x32_bf16(pa1, vb1, oc[ct], 0, 0, 0);
    }

    // commit next tile into the other buffer; single barrier per iteration
    if (kt < qt) {
      const int nxt = cur ^ 1;
      *(bf16x8*)&Ks[nxt][st0] = kp0;
      *(bf16x8*)&Ks[nxt][st1] = kp1;
      *(bf16x8*)&Vt[nxt][st0] = vp0;
      *(bf16x8*)&Vt[nxt][st1] = vp1;
    }
    __syncthreads();
  }

  // epilogue: normalize (broadcast l), write concat-heads bf16
  const int bb = bh / H_, hh = bh - (bh / H_) * H_;
#pragma unroll
  for (int i = 0; i < 4; ++i) {
    const float lv  = __shfl(l_r, lk * 4 + i);
    const float inv = 1.0f / lv;
    const int t = q0 + w * 16 + lk * 4 + i;
    ushort* orow = o_ws + ((size_t)bb * T_ + t) * E_ + hh * DH_;
#pragma unroll
    for (int ct = 0; ct < 4; ++ct)
      orow[ct * 16 + lrow] = f2bf(oc[ct][i] * inv);
  }
}

// ---------------------------------------------------------------------------
// Out-proj MFMA GEMM: out = ob @ Wp + bp  (bf16 in, f32 out)
// ---------------------------------------------------------------------------
__global__ __launch_bounds__(256) void proj_mfma_k(
    const ushort* __restrict__ ob, const ushort* __restrict__ Wpt,
    const float* __restrict__ bp, float* __restrict__ out)
{
  __shared__ __align__(16) ushort As[128 * GLD];
  __shared__ __align__(16) ushort Bs[64 * GLD];

  const int n0 = blockIdx.x * 64;
  const int m0 = blockIdx.y * 128;

  const int tid  = threadIdx.x;
  const int w    = tid >> 6, l = tid & 63;
  const int lrow = l & 15, lk = l >> 4;

  f32x4 acc[2][4] = {};

  for (int k0 = 0; k0 < E_; k0 += 64) {
#pragma unroll
    for (int it = 0; it < 4; ++it) {
      const int c = tid + it * 256;
      const int r = c >> 3, sub = c & 7;
      *(bf16x8*)&As[r * GLD + sub * 8] =
          *(const bf16x8*)(ob + (size_t)(m0 + r) * E_ + k0 + sub * 8);
    }
#pragma unroll
    for (int it = 0; it < 2; ++it) {
      const int c = tid + it * 256;
      const int r = c >> 3, sub = c & 7;
      *(bf16x8*)&Bs[r * GLD + sub * 8] =
          *(const bf16x8*)(Wpt + (size_t)(n0 + r) * E_ + k0 + sub * 8);
    }
    __syncthreads();

#pragma unroll
    for (int kk = 0; kk < 2; ++kk) {
      const bf16x8 a0 = *(const bf16x8*)&As[(w * 32 + lrow) * GLD + kk * 32 + lk * 8];
      const bf16x8 a1 = *(const bf16x8*)&As[(w * 32 + 16 + lrow) * GLD + kk * 32 + lk * 8];
#pragma unroll
      for (int ni = 0; ni < 4; ++ni) {
        const bf16x8 b = *(const bf16x8*)&Bs[(ni * 16 + lrow) * GLD + kk * 32 + lk * 8];
        acc[0][ni] = __builtin_amdgcn_mfma_f32_16x16x32_bf16(a0, b, acc[0][ni], 0, 0, 0);
        acc[1][ni] = __builtin_amdgcn_mfma_f32_16x16x32_bf16(a1, b, acc[1][ni], 0, 0, 0);
      }
    }
    __syncthreads();
  }

  float bias[4];
#pragma unroll
  for (int ni = 0; ni < 4; ++ni) bias[ni] = bp[n0 + ni * 16 + lrow];

#pragma unroll
  for (int mi = 0; mi < 2; ++mi)
#pragma unroll
    for (int i = 0; i < 4; ++i) {
      const int m = m0 + w * 32 + mi * 16 + lk * 4 + i;
      float* orow = out + (size_t)m * E_ + n0;
#pragma unroll
      for (int ni = 0; ni < 4; ++ni)
        orow[ni * 16 + lrow] = acc[mi][ni][i] + bias[ni];
    }
}

}  // namespace

extern "C" void kernel_launch(void* const* d_in, const int* in_sizes, int n_in,
                              void* d_out, int out_size, void* d_ws, size_t ws_size,
                              hipStream_t stream) {
  const float* x  = (const float*)d_in[0];
  const float* Wq = (const float*)d_in[1];
  const float* Wk = (const float*)d_in[2];
  const float* Wv = (const float*)d_in[3];
  const float* Wp = (const float*)d_in[4];
  const float* bp = (const float*)d_in[5];
  float* out = (float*)d_out;

  const size_t nx  = (size_t)M_ * E_;
  const size_t nwt = (size_t)3 * H_ * DH_ * E_;
  const size_t nwp = (size_t)E_ * E_;
  const size_t per = (size_t)B_ * H_ * T_ * DH_;

  ushort* xb    = (ushort*)d_ws;
  ushort* Wt    = xb + nx;
  ushort* Wpt   = Wt + nwt;
  ushort* q_ws  = Wpt + nwp;
  ushort* k_ws  = q_ws + per;
  ushort* vt_ws = k_ws + per;   // [bh][d][t] transposed V
  ushort* o_b   = vt_ws + per;

  convert_x_k<<<dim3((int)(nx / (256 * 8))), 256, 0, stream>>>(x, xb);
  transpose_w_k<<<dim3(576), 256, 0, stream>>>(Wq, Wk, Wv, Wp, Wt, Wpt);
  qkv_mfma_k<<<dim3(36, 32), 256, 0, stream>>>(xb, Wt, q_ws, k_ws, vt_ws);
  attn_mfma_k<<<dim3(24, 32), 256, 0, stream>>>(q_ws, k_ws, vt_ws, o_b);
  proj_mfma_k<<<dim3(12, 32), 256, 0, stream>>>(o_b, Wpt, bp, out);
}

// Round 7
// 110.640 us; speedup vs baseline: 1.6985x; 1.0428x over previous
//
#include <hip/hip_runtime.h>
#include <math.h>

namespace {

constexpr int E_  = 768;
constexpr int H_  = 12;
constexpr int DH_ = 64;
constexpr int T_  = 2048;
constexpr int B_  = 2;
constexpr int M_  = B_ * T_;  // 4096

typedef __attribute__((ext_vector_type(8))) short bf16x8;
typedef __attribute__((ext_vector_type(4))) float f32x4;

__device__ inline ushort f2bf(float f) {
  union { float f; unsigned u; } v; v.f = f;
  unsigned u = v.u + 0x7FFFu + ((v.u >> 16) & 1u);  // RNE
  return (ushort)(u >> 16);
}

// async global->LDS, 16B per lane. lds ptr must be wave-uniform base;
// HW writes base + lane*16. global ptr is per-lane (pre-swizzled source).
__device__ __forceinline__ void gl16(const ushort* g, ushort* l) {
  __builtin_amdgcn_global_load_lds(
      (const __attribute__((address_space(1))) unsigned int*)(g),
      (__attribute__((address_space(3))) unsigned int*)(l), 16, 0, 0);
}

// ---------------------------------------------------------------------------
// x f32 -> bf16, elementwise (8 per thread)
// ---------------------------------------------------------------------------
__global__ __launch_bounds__(256) void convert_x_k(
    const float* __restrict__ x, ushort* __restrict__ xb)
{
  const size_t i = ((size_t)blockIdx.x * 256 + threadIdx.x) * 8;
  float4 a = *(const float4*)(x + i);
  float4 b = *(const float4*)(x + i + 4);
  ushort o[8] = {f2bf(a.x), f2bf(a.y), f2bf(a.z), f2bf(a.w),
                 f2bf(b.x), f2bf(b.y), f2bf(b.z), f2bf(b.w)};
  *(bf16x8*)(xb + i) = *(bf16x8*)o;
}

// ---------------------------------------------------------------------------
// Weight transpose + convert: W [K][N] f32 -> Wt [N][K] bf16 (k-contiguous).
// Wt is [2304][768] with n = (mat*12+h)*64 + d;  Wpt is [768][768].
// ---------------------------------------------------------------------------
__global__ __launch_bounds__(256) void transpose_w_k(
    const float* __restrict__ Wq, const float* __restrict__ Wk,
    const float* __restrict__ Wv, const float* __restrict__ Wp,
    ushort* __restrict__ Wt, ushort* __restrict__ Wpt)
{
  __shared__ float tile[64][65];
  const int bid = blockIdx.x;
  const int tid = threadIdx.x;
  const int tr = tid >> 4, tc = tid & 15;

  const float* src; ushort* dst;
  int k0, n0, sN, dK;
  if (bid < 432) {
    const int mat = bid / 144, rem = bid % 144;
    const int h = rem / 12, ktile = rem % 12;
    const float* W = (mat == 0) ? Wq : (mat == 1) ? Wk : Wv;
    src = W + (size_t)h * E_ * DH_;
    dst = Wt + (size_t)(mat * H_ + h) * DH_ * E_;
    k0 = ktile * 64; n0 = 0; sN = DH_; dK = E_;
  } else {
    const int rem = bid - 432;
    src = Wp;
    dst = Wpt;
    k0 = (rem / 12) * 64; n0 = (rem % 12) * 64; sN = E_; dK = E_;
  }

#pragma unroll
  for (int rr = 0; rr < 64; rr += 16) {
    float4 v = *(const float4*)(src + (size_t)(k0 + tr + rr) * sN + n0 + tc * 4);
    tile[tr + rr][tc * 4 + 0] = v.x;
    tile[tr + rr][tc * 4 + 1] = v.y;
    tile[tr + rr][tc * 4 + 2] = v.z;
    tile[tr + rr][tc * 4 + 3] = v.w;
  }
  __syncthreads();
#pragma unroll
  for (int rr = 0; rr < 64; rr += 16) {
    const int n = tr + rr;
    ushort4 o;
    o.x = f2bf(tile[tc * 4 + 0][n]);
    o.y = f2bf(tile[tc * 4 + 1][n]);
    o.z = f2bf(tile[tc * 4 + 2][n]);
    o.w = f2bf(tile[tc * 4 + 3][n]);
    *(ushort4*)(dst + (size_t)(n0 + n) * dK + k0 + tc * 4) = o;
  }
}

// ---------------------------------------------------------------------------
// Unified QKV GEMM: Y[4096][2304] = xb @ Wt^T, 128x128 tiles, BK=64.
// Staging via global_load_lds(16B), linear LDS + pre-swizzled global source
// (chunk ^= row&7) -> conflict-free ds_read_b128 fragment reads.
// Epilogue scatters per 64-col segment: Q (scaled), K, V (transposed bounce).
// ---------------------------------------------------------------------------
constexpr float QSCALE = 0.18033688f;  // 1/8 * log2(e)

__global__ __launch_bounds__(256) void qkv_fused_k(
    const ushort* __restrict__ xb, const ushort* __restrict__ Wt,
    ushort* __restrict__ q_ws, ushort* __restrict__ k_ws, ushort* __restrict__ vt_ws)
{
  __shared__ __align__(16) ushort lds[2 * 128 * 64];  // As | Bs (32 KB)
  ushort* As = lds;
  ushort* Bs = lds + 128 * 64;

  const int n0 = blockIdx.x * 128;
  const int m0 = blockIdx.y * 128;

  const int tid  = threadIdx.x;
  const int w    = tid >> 6, l = tid & 63;
  const int lrow = l & 15, lk = l >> 4;
  const int r7   = lrow & 7;

  // staging geometry: per round, wave w covers rows base..base+7 (1 KB)
  const int srow = l >> 3;                 // 0..7 within wave's row group
  const int sch  = (l & 7) ^ srow;         // pre-swizzled source chunk

  f32x4 acc[2][8] = {};

  for (int k0 = 0; k0 < E_; k0 += 64) {
#pragma unroll
    for (int r = 0; r < 4; ++r) {
      const int base = r * 32 + w * 8;     // wave-uniform
      gl16(xb + (size_t)(m0 + base + srow) * E_ + k0 + sch * 8, &As[base * 64]);
      gl16(Wt + (size_t)(n0 + base + srow) * E_ + k0 + sch * 8, &Bs[base * 64]);
    }
    __syncthreads();  // drains vmcnt before barrier

#pragma unroll
    for (int kk = 0; kk < 2; ++kk) {
      const int cof = ((kk * 4 + lk) ^ r7) * 8;
      const bf16x8 a0 = *(const bf16x8*)&As[(w * 32 + lrow) * 64 + cof];
      const bf16x8 a1 = *(const bf16x8*)&As[(w * 32 + 16 + lrow) * 64 + cof];
#pragma unroll
      for (int nf = 0; nf < 8; ++nf) {
        const bf16x8 b = *(const bf16x8*)&Bs[(nf * 16 + lrow) * 64 + cof];
        acc[0][nf] = __builtin_amdgcn_mfma_f32_16x16x32_bf16(a0, b, acc[0][nf], 0, 0, 0);
        acc[1][nf] = __builtin_amdgcn_mfma_f32_16x16x32_bf16(a1, b, acc[1][nf], 0, 0, 0);
      }
    }
    __syncthreads();
  }

  // epilogue: two 64-col segments
  const int b  = m0 >> 11;         // / 2048
  const int t0 = m0 & 2047;
  ushort* Td = lds;                // [64][136] V bounce, aliases staging

#pragma unroll
  for (int half = 0; half < 2; ++half) {
    const int seg = (n0 >> 6) + half;      // 0..35
    const int mat = seg / H_;
    const int h   = seg - mat * H_;
    const int bh  = b * H_ + h;

    if (mat != 2) {
      const float qs = (mat == 0) ? QSCALE : 1.0f;
      ushort* outw = (mat == 0) ? q_ws : k_ws;
#pragma unroll
      for (int mi = 0; mi < 2; ++mi)
#pragma unroll
        for (int i = 0; i < 4; ++i) {
          const int t = t0 + w * 32 + mi * 16 + lk * 4 + i;
          ushort* orow = outw + ((size_t)bh * T_ + t) * DH_;
#pragma unroll
          for (int nf2 = 0; nf2 < 4; ++nf2)
            orow[nf2 * 16 + lrow] = f2bf(acc[mi][half * 4 + nf2][i] * qs);
        }
    } else {
      __syncthreads();  // staging reads / previous copy done
#pragma unroll
      for (int mi = 0; mi < 2; ++mi)
#pragma unroll
        for (int i = 0; i < 4; ++i) {
          const int tl = w * 32 + mi * 16 + lk * 4 + i;
#pragma unroll
          for (int nf2 = 0; nf2 < 4; ++nf2)
            Td[(nf2 * 16 + lrow) * 136 + tl] = f2bf(acc[mi][half * 4 + nf2][i]);
        }
      __syncthreads();
#pragma unroll
      for (int it = 0; it < 4; ++it) {
        const int c = tid + it * 256;
        const int d = c >> 4, sub = c & 15;
        *(bf16x8*)(vt_ws + ((size_t)bh * DH_ + d) * T_ + t0 + sub * 8) =
            *(const bf16x8*)&Td[d * 136 + sub * 8];
      }
    }
  }
}

// ---------------------------------------------------------------------------
// Causal flash attention (R6 structure; softmax reductions tree-ified).
// ---------------------------------------------------------------------------
__global__ __launch_bounds__(256) void attn_mfma_k(
    const ushort* __restrict__ q_ws, const ushort* __restrict__ k_ws,
    const ushort* __restrict__ vt_ws, ushort* __restrict__ o_ws)
{
  __shared__ __align__(16) ushort Ks[2][64 * 64];
  __shared__ __align__(16) ushort Vt[2][64 * 64];
  __shared__ __align__(16) ushort Pl[4][16 * 64];

  const int qt = 31 - (int)blockIdx.y;
  const int bh = blockIdx.x;
  const int q0 = qt * 64;
  const ushort* Qb  = q_ws + (size_t)bh * T_ * DH_;
  const ushort* Kb  = k_ws + (size_t)bh * T_ * DH_;
  const ushort* VTb = vt_ws + (size_t)bh * DH_ * T_;

  const int tid  = threadIdx.x;
  const int w    = tid >> 6;
  const int l    = tid & 63;
  const int lrow = l & 15;
  const int lk   = l >> 4;
  const int r7   = lrow & 7;
  const int rr   = tid >> 3;
  const int sub  = tid & 7;
  const int swc  = sub ^ (rr & 7);

  const int st0 = rr * 64 + swc * 8;
  const int st1 = (rr + 32) * 64 + swc * 8;

  int kof0[4], kof1[4];
#pragma unroll
  for (int ct = 0; ct < 4; ++ct) {
    kof0[ct] = (ct * 16 + lrow) * 64 + ((lk ^ r7) * 8);
    kof1[ct] = (ct * 16 + lrow) * 64 + (((lk + 4) ^ r7) * 8);
  }

  const ushort* Qrow = Qb + (size_t)(q0 + w * 16 + lrow) * DH_;
  const bf16x8 qa0 = *(const bf16x8*)(Qrow + lk * 8);
  const bf16x8 qa1 = *(const bf16x8*)(Qrow + lk * 8 + 32);
  const int qglob = q0 + w * 16 + lrow;

  float m_r = -INFINITY, l_r = 0.f;
  f32x4 oc[4] = {};

  ushort* Pw = &Pl[w][0];
  const int rd0 = lrow * 64 + ((lk ^ r7) * 8);
  const int rd1 = lrow * 64 + (((lk + 4) ^ r7) * 8);
  const int wrbase  = lrow * 128 + (lk & 1) * 8;
  const int wrchunk = (lk >> 1);

  bf16x8 kp0 = *(const bf16x8*)(Kb + (size_t)rr * DH_ + sub * 8);
  bf16x8 kp1 = *(const bf16x8*)(Kb + (size_t)(rr + 32) * DH_ + sub * 8);
  bf16x8 vp0 = *(const bf16x8*)(VTb + (size_t)rr * T_ + sub * 8);
  bf16x8 vp1 = *(const bf16x8*)(VTb + (size_t)(rr + 32) * T_ + sub * 8);
  *(bf16x8*)&Ks[0][st0] = kp0;
  *(bf16x8*)&Ks[0][st1] = kp1;
  *(bf16x8*)&Vt[0][st0] = vp0;
  *(bf16x8*)&Vt[0][st1] = vp1;
  __syncthreads();

  for (int kt = 0; kt <= qt; ++kt) {
    const int s0  = kt * 64;
    const int cur = kt & 1;

    if (kt < qt) {
      const int sn = s0 + 64;
      kp0 = *(const bf16x8*)(Kb + (size_t)(sn + rr) * DH_ + sub * 8);
      kp1 = *(const bf16x8*)(Kb + (size_t)(sn + rr + 32) * DH_ + sub * 8);
      vp0 = *(const bf16x8*)(VTb + (size_t)rr * T_ + sn + sub * 8);
      vp1 = *(const bf16x8*)(VTb + (size_t)(rr + 32) * T_ + sn + sub * 8);
    }

    f32x4 st[4];
#pragma unroll
    for (int ct = 0; ct < 4; ++ct) {
      const bf16x8 kb0 = *(const bf16x8*)&Ks[cur][kof0[ct]];
      const bf16x8 kb1 = *(const bf16x8*)&Ks[cur][kof1[ct]];
      f32x4 z = {0.f, 0.f, 0.f, 0.f};
      z = __builtin_amdgcn_mfma_f32_16x16x32_bf16(kb0, qa0, z, 0, 0, 0);
      st[ct] = __builtin_amdgcn_mfma_f32_16x16x32_bf16(kb1, qa1, z, 0, 0, 0);
    }

    if (kt == qt) {
#pragma unroll
      for (int ct = 0; ct < 4; ++ct)
#pragma unroll
        for (int i = 0; i < 4; ++i)
          if (s0 + ct * 16 + lk * 4 + i > qglob) st[ct][i] = -INFINITY;
    }

    // row max: tree (depth 4) + 2 shuffles
    float mc[4];
#pragma unroll
    for (int ct = 0; ct < 4; ++ct)
      mc[ct] = fmaxf(fmaxf(st[ct][0], st[ct][1]), fmaxf(st[ct][2], st[ct][3]));
    float mx = fmaxf(fmaxf(mc[0], mc[1]), fmaxf(mc[2], mc[3]));
    mx = fmaxf(mx, __shfl_xor(mx, 16));
    mx = fmaxf(mx, __shfl_xor(mx, 32));

    if (__any(mx > m_r + 8.f)) {
      const float mn   = fmaxf(m_r, mx);
      const float corr = exp2f(m_r - mn);
      m_r = mn;
      l_r *= corr;
#pragma unroll
      for (int i = 0; i < 4; ++i) {
        const float cr = __shfl(corr, lk * 4 + i);
#pragma unroll
        for (int ct = 0; ct < 4; ++ct) oc[ct][i] *= cr;
      }
    }

    // exp2 + sum: tree
    float sc[4];
#pragma unroll
    for (int ct = 0; ct < 4; ++ct) {
#pragma unroll
      for (int i = 0; i < 4; ++i) st[ct][i] = exp2f(st[ct][i] - m_r);
      sc[ct] = (st[ct][0] + st[ct][1]) + (st[ct][2] + st[ct][3]);
    }
    float rs = (sc[0] + sc[1]) + (sc[2] + sc[3]);
    rs += __shfl_xor(rs, 16);
    rs += __shfl_xor(rs, 32);
    l_r += rs;

#pragma unroll
    for (int ct = 0; ct < 4; ++ct) {
      unsigned lo, hi;
      asm("v_cvt_pk_bf16_f32 %0, %1, %2" : "=v"(lo) : "v"(st[ct][0]), "v"(st[ct][1]));
      asm("v_cvt_pk_bf16_f32 %0, %1, %2" : "=v"(hi) : "v"(st[ct][2]), "v"(st[ct][3]));
      uint2 pk; pk.x = lo; pk.y = hi;
      const int ch = ((ct * 2 + wrchunk) ^ r7);
      *(uint2*)((char*)Pw + wrbase + ch * 16) = pk;
    }

    const bf16x8 pa0 = *(const bf16x8*)(Pw + rd0);
    const bf16x8 pa1 = *(const bf16x8*)(Pw + rd1);

#pragma unroll
    for (int ct = 0; ct < 4; ++ct) {
      const bf16x8 vb0 = *(const bf16x8*)&Vt[cur][kof0[ct]];
      const bf16x8 vb1 = *(const bf16x8*)&Vt[cur][kof1[ct]];
      oc[ct] = __builtin_amdgcn_mfma_f32_16x16x32_bf16(pa0, vb0, oc[ct], 0, 0, 0);
      oc[ct] = __builtin_amdgcn_mfma_f32_16x16x32_bf16(pa1, vb1, oc[ct], 0, 0, 0);
    }

    if (kt < qt) {
      const int nxt = cur ^ 1;
      *(bf16x8*)&Ks[nxt][st0] = kp0;
      *(bf16x8*)&Ks[nxt][st1] = kp1;
      *(bf16x8*)&Vt[nxt][st0] = vp0;
      *(bf16x8*)&Vt[nxt][st1] = vp1;
    }
    __syncthreads();
  }

  const int bb = bh / H_, hh = bh - (bh / H_) * H_;
#pragma unroll
  for (int i = 0; i < 4; ++i) {
    const float lv  = __shfl(l_r, lk * 4 + i);
    const float inv = 1.0f / lv;
    const int t = q0 + w * 16 + lk * 4 + i;
    ushort* orow = o_ws + ((size_t)bb * T_ + t) * E_ + hh * DH_;
#pragma unroll
    for (int ct = 0; ct < 4; ++ct)
      orow[ct * 16 + lrow] = f2bf(oc[ct][i] * inv);
  }
}

// ---------------------------------------------------------------------------
// Out-proj GEMM: out = ob @ Wp + bp. Same gload_lds 128x128 structure.
// ---------------------------------------------------------------------------
__global__ __launch_bounds__(256) void proj2_k(
    const ushort* __restrict__ ob, const ushort* __restrict__ Wpt,
    const float* __restrict__ bp, float* __restrict__ out)
{
  __shared__ __align__(16) ushort lds[2 * 128 * 64];
  ushort* As = lds;
  ushort* Bs = lds + 128 * 64;

  const int n0 = blockIdx.x * 128;
  const int m0 = blockIdx.y * 128;

  const int tid  = threadIdx.x;
  const int w    = tid >> 6, l = tid & 63;
  const int lrow = l & 15, lk = l >> 4;
  const int r7   = lrow & 7;
  const int srow = l >> 3;
  const int sch  = (l & 7) ^ srow;

  f32x4 acc[2][8] = {};

  for (int k0 = 0; k0 < E_; k0 += 64) {
#pragma unroll
    for (int r = 0; r < 4; ++r) {
      const int base = r * 32 + w * 8;
      gl16(ob  + (size_t)(m0 + base + srow) * E_ + k0 + sch * 8, &As[base * 64]);
      gl16(Wpt + (size_t)(n0 + base + srow) * E_ + k0 + sch * 8, &Bs[base * 64]);
    }
    __syncthreads();

#pragma unroll
    for (int kk = 0; kk < 2; ++kk) {
      const int cof = ((kk * 4 + lk) ^ r7) * 8;
      const bf16x8 a0 = *(const bf16x8*)&As[(w * 32 + lrow) * 64 + cof];
      const bf16x8 a1 = *(const bf16x8*)&As[(w * 32 + 16 + lrow) * 64 + cof];
#pragma unroll
      for (int nf = 0; nf < 8; ++nf) {
        const bf16x8 b = *(const bf16x8*)&Bs[(nf * 16 + lrow) * 64 + cof];
        acc[0][nf] = __builtin_amdgcn_mfma_f32_16x16x32_bf16(a0, b, acc[0][nf], 0, 0, 0);
        acc[1][nf] = __builtin_amdgcn_mfma_f32_16x16x32_bf16(a1, b, acc[1][nf], 0, 0, 0);
      }
    }
    __syncthreads();
  }

  float bias[8];
#pragma unroll
  for (int nf = 0; nf < 8; ++nf) bias[nf] = bp[n0 + nf * 16 + lrow];

#pragma unroll
  for (int mi = 0; mi < 2; ++mi)
#pragma unroll
    for (int i = 0; i < 4; ++i) {
      const int m = m0 + w * 32 + mi * 16 + lk * 4 + i;
      float* orow = out + (size_t)m * E_ + n0;
#pragma unroll
      for (int nf = 0; nf < 8; ++nf)
        orow[nf * 16 + lrow] = acc[mi][nf][i] + bias[nf];
    }
}

}  // namespace

extern "C" void kernel_launch(void* const* d_in, const int* in_sizes, int n_in,
                              void* d_out, int out_size, void* d_ws, size_t ws_size,
                              hipStream_t stream) {
  const float* x  = (const float*)d_in[0];
  const float* Wq = (const float*)d_in[1];
  const float* Wk = (const float*)d_in[2];
  const float* Wv = (const float*)d_in[3];
  const float* Wp = (const float*)d_in[4];
  const float* bp = (const float*)d_in[5];
  float* out = (float*)d_out;

  const size_t nx  = (size_t)M_ * E_;
  const size_t nwt = (size_t)3 * H_ * DH_ * E_;
  const size_t nwp = (size_t)E_ * E_;
  const size_t per = (size_t)B_ * H_ * T_ * DH_;

  ushort* xb    = (ushort*)d_ws;
  ushort* Wt    = xb + nx;      // [2304][768]
  ushort* Wpt   = Wt + nwt;     // [768][768]
  ushort* q_ws  = Wpt + nwp;
  ushort* k_ws  = q_ws + per;
  ushort* vt_ws = k_ws + per;   // [bh][d][t]
  ushort* o_b   = vt_ws + per;

  convert_x_k<<<dim3((int)(nx / (256 * 8))), 256, 0, stream>>>(x, xb);
  transpose_w_k<<<dim3(576), 256, 0, stream>>>(Wq, Wk, Wv, Wp, Wt, Wpt);
  qkv_fused_k<<<dim3(18, 32), 256, 0, stream>>>(xb, Wt, q_ws, k_ws, vt_ws);
  attn_mfma_k<<<dim3(24, 32), 256, 0, stream>>>(q_ws, k_ws, vt_ws, o_b);
  proj2_k<<<dim3(6, 32), 256, 0, stream>>>(o_b, Wpt, bp, out);
}

// Round 8
// 102.277 us; speedup vs baseline: 1.8374x; 1.0818x over previous
//
#include <hip/hip_runtime.h>
#include <math.h>

namespace {

constexpr int E_  = 768;
constexpr int H_  = 12;
constexpr int DH_ = 64;
constexpr int T_  = 2048;
constexpr int B_  = 2;
constexpr int M_  = B_ * T_;  // 4096
constexpr int BH_ = B_ * H_;  // 24

typedef __attribute__((ext_vector_type(8))) short bf16x8;
typedef __attribute__((ext_vector_type(4))) float f32x4;

__device__ inline ushort f2bf(float f) {
  union { float f; unsigned u; } v; v.f = f;
  unsigned u = v.u + 0x7FFFu + ((v.u >> 16) & 1u);  // RNE
  return (ushort)(u >> 16);
}
__device__ inline float bf2f(ushort u) {
  union { unsigned u; float f; } v; v.u = (unsigned)u << 16; return v.f;
}

// async global->LDS, 16B per lane (wave-uniform LDS base, per-lane global src)
__device__ __forceinline__ void gl16(const ushort* g, ushort* l) {
  __builtin_amdgcn_global_load_lds(
      (const __attribute__((address_space(1))) unsigned int*)(g),
      (__attribute__((address_space(3))) unsigned int*)(l), 16, 0, 0);
}

// ---------------------------------------------------------------------------
// prep: blocks [0,1536) convert x f32->bf16; blocks [1536,2112) transpose W.
// ---------------------------------------------------------------------------
constexpr int NCONV = 1536;

__global__ __launch_bounds__(256) void prep_k(
    const float* __restrict__ x,
    const float* __restrict__ Wq, const float* __restrict__ Wk,
    const float* __restrict__ Wv, const float* __restrict__ Wp,
    ushort* __restrict__ xb, ushort* __restrict__ Wt, ushort* __restrict__ Wpt)
{
  __shared__ float tile[64][65];
  const int bid = blockIdx.x;
  const int tid = threadIdx.x;

  if (bid < NCONV) {
    const size_t i = ((size_t)bid * 256 + tid) * 8;
    float4 a = *(const float4*)(x + i);
    float4 b = *(const float4*)(x + i + 4);
    ushort o[8] = {f2bf(a.x), f2bf(a.y), f2bf(a.z), f2bf(a.w),
                   f2bf(b.x), f2bf(b.y), f2bf(b.z), f2bf(b.w)};
    *(bf16x8*)(xb + i) = *(bf16x8*)o;
    return;
  }

  const int wb = bid - NCONV;  // 0..575
  const int tr = tid >> 4, tc = tid & 15;
  const float* src; ushort* dst;
  int k0, n0, sN, dK;
  if (wb < 432) {
    const int mat = wb / 144, rem = wb % 144;
    const int h = rem / 12, ktile = rem % 12;
    const float* W = (mat == 0) ? Wq : (mat == 1) ? Wk : Wv;
    src = W + (size_t)h * E_ * DH_;
    dst = Wt + (size_t)(mat * H_ + h) * DH_ * E_;
    k0 = ktile * 64; n0 = 0; sN = DH_; dK = E_;
  } else {
    const int rem = wb - 432;
    src = Wp;
    dst = Wpt;
    k0 = (rem / 12) * 64; n0 = (rem % 12) * 64; sN = E_; dK = E_;
  }

#pragma unroll
  for (int rr = 0; rr < 64; rr += 16) {
    float4 v = *(const float4*)(src + (size_t)(k0 + tr + rr) * sN + n0 + tc * 4);
    tile[tr + rr][tc * 4 + 0] = v.x;
    tile[tr + rr][tc * 4 + 1] = v.y;
    tile[tr + rr][tc * 4 + 2] = v.z;
    tile[tr + rr][tc * 4 + 3] = v.w;
  }
  __syncthreads();
#pragma unroll
  for (int rr = 0; rr < 64; rr += 16) {
    const int n = tr + rr;
    ushort4 o;
    o.x = f2bf(tile[tc * 4 + 0][n]);
    o.y = f2bf(tile[tc * 4 + 1][n]);
    o.z = f2bf(tile[tc * 4 + 2][n]);
    o.w = f2bf(tile[tc * 4 + 3][n]);
    *(ushort4*)(dst + (size_t)(n0 + n) * dK + k0 + tc * 4) = o;
  }
}

// ---------------------------------------------------------------------------
// Unified QKV GEMM (unchanged from R7): 128x128 tiles, gload_lds staging.
// ---------------------------------------------------------------------------
constexpr float QSCALE = 0.18033688f;  // 1/8 * log2(e)

__global__ __launch_bounds__(256) void qkv_fused_k(
    const ushort* __restrict__ xb, const ushort* __restrict__ Wt,
    ushort* __restrict__ q_ws, ushort* __restrict__ k_ws, ushort* __restrict__ vt_ws)
{
  __shared__ __align__(16) ushort lds[2 * 128 * 64];
  ushort* As = lds;
  ushort* Bs = lds + 128 * 64;

  const int n0 = blockIdx.x * 128;
  const int m0 = blockIdx.y * 128;

  const int tid  = threadIdx.x;
  const int w    = tid >> 6, l = tid & 63;
  const int lrow = l & 15, lk = l >> 4;
  const int r7   = lrow & 7;
  const int srow = l >> 3;
  const int sch  = (l & 7) ^ srow;

  f32x4 acc[2][8] = {};

  for (int k0 = 0; k0 < E_; k0 += 64) {
#pragma unroll
    for (int r = 0; r < 4; ++r) {
      const int base = r * 32 + w * 8;
      gl16(xb + (size_t)(m0 + base + srow) * E_ + k0 + sch * 8, &As[base * 64]);
      gl16(Wt + (size_t)(n0 + base + srow) * E_ + k0 + sch * 8, &Bs[base * 64]);
    }
    __syncthreads();

#pragma unroll
    for (int kk = 0; kk < 2; ++kk) {
      const int cof = ((kk * 4 + lk) ^ r7) * 8;
      const bf16x8 a0 = *(const bf16x8*)&As[(w * 32 + lrow) * 64 + cof];
      const bf16x8 a1 = *(const bf16x8*)&As[(w * 32 + 16 + lrow) * 64 + cof];
#pragma unroll
      for (int nf = 0; nf < 8; ++nf) {
        const bf16x8 b = *(const bf16x8*)&Bs[(nf * 16 + lrow) * 64 + cof];
        acc[0][nf] = __builtin_amdgcn_mfma_f32_16x16x32_bf16(a0, b, acc[0][nf], 0, 0, 0);
        acc[1][nf] = __builtin_amdgcn_mfma_f32_16x16x32_bf16(a1, b, acc[1][nf], 0, 0, 0);
      }
    }
    __syncthreads();
  }

  const int b  = m0 >> 11;
  const int t0 = m0 & 2047;
  ushort* Td = lds;

#pragma unroll
  for (int half = 0; half < 2; ++half) {
    const int seg = (n0 >> 6) + half;
    const int mat = seg / H_;
    const int h   = seg - mat * H_;
    const int bh  = b * H_ + h;

    if (mat != 2) {
      const float qs = (mat == 0) ? QSCALE : 1.0f;
      ushort* outw = (mat == 0) ? q_ws : k_ws;
#pragma unroll
      for (int mi = 0; mi < 2; ++mi)
#pragma unroll
        for (int i = 0; i < 4; ++i) {
          const int t = t0 + w * 32 + mi * 16 + lk * 4 + i;
          ushort* orow = outw + ((size_t)bh * T_ + t) * DH_;
#pragma unroll
          for (int nf2 = 0; nf2 < 4; ++nf2)
            orow[nf2 * 16 + lrow] = f2bf(acc[mi][half * 4 + nf2][i] * qs);
        }
    } else {
      __syncthreads();
#pragma unroll
      for (int mi = 0; mi < 2; ++mi)
#pragma unroll
        for (int i = 0; i < 4; ++i) {
          const int tl = w * 32 + mi * 16 + lk * 4 + i;
#pragma unroll
          for (int nf2 = 0; nf2 < 4; ++nf2)
            Td[(nf2 * 16 + lrow) * 136 + tl] = f2bf(acc[mi][half * 4 + nf2][i]);
        }
      __syncthreads();
#pragma unroll
      for (int it = 0; it < 4; ++it) {
        const int c = tid + it * 256;
        const int d = c >> 4, sub = c & 15;
        *(bf16x8*)(vt_ws + ((size_t)bh * DH_ + d) * T_ + t0 + sub * 8) =
            *(const bf16x8*)&Td[d * 136 + sub * 8];
      }
    }
  }
}

// ---------------------------------------------------------------------------
// Causal flash attention with k-range split x2 (doubles wave concurrency:
// 3 -> 6 waves/SIMD). Each block computes UNNORMALIZED partial O (bf16) and
// per-row (m,l); attn_combine_k merges. Single-buffered K/V (24KB LDS ->
// 6 blocks/CU), XOR-swizzled tiles, per-wave swizzled P bounce, defer-max.
// grid (x=bh 24, y: qt=31-y, z: k-half).
// ---------------------------------------------------------------------------
__global__ __launch_bounds__(256) void attn_split_k(
    const ushort* __restrict__ q_ws, const ushort* __restrict__ k_ws,
    const ushort* __restrict__ vt_ws, ushort* __restrict__ op_ws,
    float2* __restrict__ ml_ws)
{
  __shared__ __align__(16) ushort Ks[64 * 64];
  __shared__ __align__(16) ushort Vt[64 * 64];
  __shared__ __align__(16) ushort Pl[4][16 * 64];

  const int qt = 31 - (int)blockIdx.y;
  const int bh = blockIdx.x;
  const int hz = blockIdx.z;
  const int nt = qt + 1;
  const int klo = hz ? (nt >> 1) : 0;
  const int khi = hz ? nt : (nt >> 1);
  const int q0 = qt * 64;

  const ushort* Qb  = q_ws + (size_t)bh * T_ * DH_;
  const ushort* Kb  = k_ws + (size_t)bh * T_ * DH_;
  const ushort* VTb = vt_ws + (size_t)bh * DH_ * T_;

  const int tid  = threadIdx.x;
  const int w    = tid >> 6;
  const int l    = tid & 63;
  const int lrow = l & 15;
  const int lk   = l >> 4;
  const int r7   = lrow & 7;
  const int rr   = tid >> 3;       // staging rows rr, rr+32
  const int sub  = tid & 7;
  const int swc  = sub ^ (rr & 7);

  const int st0 = rr * 64 + swc * 8;
  const int st1 = (rr + 32) * 64 + swc * 8;

  int kof0[4], kof1[4];
#pragma unroll
  for (int ct = 0; ct < 4; ++ct) {
    kof0[ct] = (ct * 16 + lrow) * 64 + ((lk ^ r7) * 8);
    kof1[ct] = (ct * 16 + lrow) * 64 + (((lk + 4) ^ r7) * 8);
  }

  const ushort* Qrow = Qb + (size_t)(q0 + w * 16 + lrow) * DH_;
  const bf16x8 qa0 = *(const bf16x8*)(Qrow + lk * 8);
  const bf16x8 qa1 = *(const bf16x8*)(Qrow + lk * 8 + 32);
  const int qglob = q0 + w * 16 + lrow;

  float m_r = -INFINITY, l_r = 0.f;
  f32x4 oc[4] = {};

  ushort* Pw = &Pl[w][0];
  const int rd0 = lrow * 64 + ((lk ^ r7) * 8);
  const int rd1 = lrow * 64 + (((lk + 4) ^ r7) * 8);
  const int wrbase  = lrow * 128 + (lk & 1) * 8;
  const int wrchunk = (lk >> 1);

  if (klo < khi) {
    // prologue: tile klo -> regs
    bf16x8 kp0 = *(const bf16x8*)(Kb + (size_t)(klo * 64 + rr) * DH_ + sub * 8);
    bf16x8 kp1 = *(const bf16x8*)(Kb + (size_t)(klo * 64 + rr + 32) * DH_ + sub * 8);
    bf16x8 vp0 = *(const bf16x8*)(VTb + (size_t)rr * T_ + klo * 64 + sub * 8);
    bf16x8 vp1 = *(const bf16x8*)(VTb + (size_t)(rr + 32) * T_ + klo * 64 + sub * 8);

    for (int kt = klo; kt < khi; ++kt) {
      const int s0 = kt * 64;

      // commit staged regs -> LDS; barrier opens compute phase
      *(bf16x8*)&Ks[st0] = kp0;
      *(bf16x8*)&Ks[st1] = kp1;
      *(bf16x8*)&Vt[st0] = vp0;
      *(bf16x8*)&Vt[st1] = vp1;
      __syncthreads();

      // issue next tile's global loads; latency hides under compute
      if (kt + 1 < khi) {
        const int sn = s0 + 64;
        kp0 = *(const bf16x8*)(Kb + (size_t)(sn + rr) * DH_ + sub * 8);
        kp1 = *(const bf16x8*)(Kb + (size_t)(sn + rr + 32) * DH_ + sub * 8);
        vp0 = *(const bf16x8*)(VTb + (size_t)rr * T_ + sn + sub * 8);
        vp1 = *(const bf16x8*)(VTb + (size_t)(rr + 32) * T_ + sn + sub * 8);
      }

      // S^T = K Q^T
      f32x4 st[4];
#pragma unroll
      for (int ct = 0; ct < 4; ++ct) {
        const bf16x8 kb0 = *(const bf16x8*)&Ks[kof0[ct]];
        const bf16x8 kb1 = *(const bf16x8*)&Ks[kof1[ct]];
        f32x4 z = {0.f, 0.f, 0.f, 0.f};
        z = __builtin_amdgcn_mfma_f32_16x16x32_bf16(kb0, qa0, z, 0, 0, 0);
        st[ct] = __builtin_amdgcn_mfma_f32_16x16x32_bf16(kb1, qa1, z, 0, 0, 0);
      }

      if (kt == qt) {  // diagonal tile only
#pragma unroll
        for (int ct = 0; ct < 4; ++ct)
#pragma unroll
          for (int i = 0; i < 4; ++i)
            if (s0 + ct * 16 + lk * 4 + i > qglob) st[ct][i] = -INFINITY;
      }

      float mc[4];
#pragma unroll
      for (int ct = 0; ct < 4; ++ct)
        mc[ct] = fmaxf(fmaxf(st[ct][0], st[ct][1]), fmaxf(st[ct][2], st[ct][3]));
      float mx = fmaxf(fmaxf(mc[0], mc[1]), fmaxf(mc[2], mc[3]));
      mx = fmaxf(mx, __shfl_xor(mx, 16));
      mx = fmaxf(mx, __shfl_xor(mx, 32));

      if (__any(mx > m_r + 8.f)) {
        const float mn   = fmaxf(m_r, mx);
        const float corr = exp2f(m_r - mn);
        m_r = mn;
        l_r *= corr;
#pragma unroll
        for (int i = 0; i < 4; ++i) {
          const float cr = __shfl(corr, lk * 4 + i);
#pragma unroll
          for (int ct = 0; ct < 4; ++ct) oc[ct][i] *= cr;
        }
      }

      float sc[4];
#pragma unroll
      for (int ct = 0; ct < 4; ++ct) {
#pragma unroll
        for (int i = 0; i < 4; ++i) st[ct][i] = exp2f(st[ct][i] - m_r);
        sc[ct] = (st[ct][0] + st[ct][1]) + (st[ct][2] + st[ct][3]);
      }
      float rs = (sc[0] + sc[1]) + (sc[2] + sc[3]);
      rs += __shfl_xor(rs, 16);
      rs += __shfl_xor(rs, 32);
      l_r += rs;

#pragma unroll
      for (int ct = 0; ct < 4; ++ct) {
        unsigned lo, hi;
        asm("v_cvt_pk_bf16_f32 %0, %1, %2" : "=v"(lo) : "v"(st[ct][0]), "v"(st[ct][1]));
        asm("v_cvt_pk_bf16_f32 %0, %1, %2" : "=v"(hi) : "v"(st[ct][2]), "v"(st[ct][3]));
        uint2 pk; pk.x = lo; pk.y = hi;
        const int ch = ((ct * 2 + wrchunk) ^ r7);
        *(uint2*)((char*)Pw + wrbase + ch * 16) = pk;
      }

      const bf16x8 pa0 = *(const bf16x8*)(Pw + rd0);
      const bf16x8 pa1 = *(const bf16x8*)(Pw + rd1);

#pragma unroll
      for (int ct = 0; ct < 4; ++ct) {
        const bf16x8 vb0 = *(const bf16x8*)&Vt[kof0[ct]];
        const bf16x8 vb1 = *(const bf16x8*)&Vt[kof1[ct]];
        oc[ct] = __builtin_amdgcn_mfma_f32_16x16x32_bf16(pa0, vb0, oc[ct], 0, 0, 0);
        oc[ct] = __builtin_amdgcn_mfma_f32_16x16x32_bf16(pa1, vb1, oc[ct], 0, 0, 0);
      }
      __syncthreads();  // all reads of Ks/Vt done before next commit
    }
  }

  // epilogue: write UNNORMALIZED partial O + per-row (m,l)
  const size_t pb = (size_t)(hz * BH_ + bh) * T_;
  if (lk == 0)
    ml_ws[pb + q0 + w * 16 + lrow] = make_float2(m_r, l_r);
#pragma unroll
  for (int i = 0; i < 4; ++i) {
    const int t = q0 + w * 16 + lk * 4 + i;
    ushort* orow = op_ws + (pb + t) * DH_;
#pragma unroll
    for (int ct = 0; ct < 4; ++ct)
      orow[ct * 16 + lrow] = f2bf(oc[ct][i]);
  }
}

// ---------------------------------------------------------------------------
// Combine the two k-half partials -> concat-heads bf16 o_ws.
// ---------------------------------------------------------------------------
__global__ __launch_bounds__(256) void attn_combine_k(
    const ushort* __restrict__ op_ws, const float2* __restrict__ ml_ws,
    ushort* __restrict__ o_ws)
{
  const int bh = blockIdx.x;
  const int t  = blockIdx.y * 64 + (threadIdx.x >> 2);
  const int d0 = (threadIdx.x & 3) * 16;

  const size_t ixA = (size_t)bh * T_ + t;
  const size_t ixB = (size_t)(BH_ + bh) * T_ + t;
  const float2 mlA = ml_ws[ixA];
  const float2 mlB = ml_ws[ixB];
  const float m   = fmaxf(mlA.x, mlB.x);
  const float wA  = exp2f(mlA.x - m);
  const float wB  = exp2f(mlB.x - m);
  const float inv = 1.0f / (wA * mlA.y + wB * mlB.y);

  const ushort* pA = op_ws + ixA * DH_ + d0;
  const ushort* pB = op_ws + ixB * DH_ + d0;
  bf16x8 a0 = *(const bf16x8*)pA;
  bf16x8 a1 = *(const bf16x8*)(pA + 8);
  bf16x8 b0 = *(const bf16x8*)pB;
  bf16x8 b1 = *(const bf16x8*)(pB + 8);

  ushort o[16];
#pragma unroll
  for (int j = 0; j < 8; ++j) {
    o[j]     = f2bf((wA * bf2f((ushort)a0[j]) + wB * bf2f((ushort)b0[j])) * inv);
    o[8 + j] = f2bf((wA * bf2f((ushort)a1[j]) + wB * bf2f((ushort)b1[j])) * inv);
  }
  const int bb = bh / H_, hh = bh - (bh / H_) * H_;
  ushort* po = o_ws + ((size_t)bb * T_ + t) * E_ + hh * DH_ + d0;
  *(bf16x8*)po       = *(const bf16x8*)&o[0];
  *(bf16x8*)(po + 8) = *(const bf16x8*)&o[8];
}

// ---------------------------------------------------------------------------
// Out-proj GEMM (unchanged from R7).
// ---------------------------------------------------------------------------
__global__ __launch_bounds__(256) void proj2_k(
    const ushort* __restrict__ ob, const ushort* __restrict__ Wpt,
    const float* __restrict__ bp, float* __restrict__ out)
{
  __shared__ __align__(16) ushort lds[2 * 128 * 64];
  ushort* As = lds;
  ushort* Bs = lds + 128 * 64;

  const int n0 = blockIdx.x * 128;
  const int m0 = blockIdx.y * 128;

  const int tid  = threadIdx.x;
  const int w    = tid >> 6, l = tid & 63;
  const int lrow = l & 15, lk = l >> 4;
  const int r7   = lrow & 7;
  const int srow = l >> 3;
  const int sch  = (l & 7) ^ srow;

  f32x4 acc[2][8] = {};

  for (int k0 = 0; k0 < E_; k0 += 64) {
#pragma unroll
    for (int r = 0; r < 4; ++r) {
      const int base = r * 32 + w * 8;
      gl16(ob  + (size_t)(m0 + base + srow) * E_ + k0 + sch * 8, &As[base * 64]);
      gl16(Wpt + (size_t)(n0 + base + srow) * E_ + k0 + sch * 8, &Bs[base * 64]);
    }
    __syncthreads();

#pragma unroll
    for (int kk = 0; kk < 2; ++kk) {
      const int cof = ((kk * 4 + lk) ^ r7) * 8;
      const bf16x8 a0 = *(const bf16x8*)&As[(w * 32 + lrow) * 64 + cof];
      const bf16x8 a1 = *(const bf16x8*)&As[(w * 32 + 16 + lrow) * 64 + cof];
#pragma unroll
      for (int nf = 0; nf < 8; ++nf) {
        const bf16x8 b = *(const bf16x8*)&Bs[(nf * 16 + lrow) * 64 + cof];
        acc[0][nf] = __builtin_amdgcn_mfma_f32_16x16x32_bf16(a0, b, acc[0][nf], 0, 0, 0);
        acc[1][nf] = __builtin_amdgcn_mfma_f32_16x16x32_bf16(a1, b, acc[1][nf], 0, 0, 0);
      }
    }
    __syncthreads();
  }

  float bias[8];
#pragma unroll
  for (int nf = 0; nf < 8; ++nf) bias[nf] = bp[n0 + nf * 16 + lrow];

#pragma unroll
  for (int mi = 0; mi < 2; ++mi)
#pragma unroll
    for (int i = 0; i < 4; ++i) {
      const int m = m0 + w * 32 + mi * 16 + lk * 4 + i;
      float* orow = out + (size_t)m * E_ + n0;
#pragma unroll
      for (int nf = 0; nf < 8; ++nf)
        orow[nf * 16 + lrow] = acc[mi][nf][i] + bias[nf];
    }
}

}  // namespace

extern "C" void kernel_launch(void* const* d_in, const int* in_sizes, int n_in,
                              void* d_out, int out_size, void* d_ws, size_t ws_size,
                              hipStream_t stream) {
  const float* x  = (const float*)d_in[0];
  const float* Wq = (const float*)d_in[1];
  const float* Wk = (const float*)d_in[2];
  const float* Wv = (const float*)d_in[3];
  const float* Wp = (const float*)d_in[4];
  const float* bp = (const float*)d_in[5];
  float* out = (float*)d_out;

  const size_t nx  = (size_t)M_ * E_;            // 3,145,728
  const size_t nwt = (size_t)3 * H_ * DH_ * E_;  // 1,769,472
  const size_t nwp = (size_t)E_ * E_;            // 589,824
  const size_t per = (size_t)BH_ * T_ * DH_;     // 3,145,728

  ushort* xb    = (ushort*)d_ws;
  ushort* Wt    = xb + nx;
  ushort* Wpt   = Wt + nwt;
  ushort* q_ws  = Wpt + nwp;
  ushort* k_ws  = q_ws + per;
  ushort* vt_ws = k_ws + per;     // [bh][d][t]
  ushort* o_b   = vt_ws + per;    // combined attn out [b][t][E]
  ushort* op_ws = o_b + per;      // [2][bh][t][64] partials
  float2* ml_ws = (float2*)(op_ws + 2 * per);  // [2][bh][t]

  prep_k<<<dim3(NCONV + 576), 256, 0, stream>>>(x, Wq, Wk, Wv, Wp, xb, Wt, Wpt);
  qkv_fused_k<<<dim3(18, 32), 256, 0, stream>>>(xb, Wt, q_ws, k_ws, vt_ws);
  attn_split_k<<<dim3(24, 32, 2), 256, 0, stream>>>(q_ws, k_ws, vt_ws, op_ws, ml_ws);
  attn_combine_k<<<dim3(24, 32), 256, 0, stream>>>(op_ws, ml_ws, o_b);
  proj2_k<<<dim3(6, 32), 256, 0, stream>>>(o_b, Wpt, bp, out);
}

// Round 9
// 92.727 us; speedup vs baseline: 2.0266x; 1.1030x over previous
//
#include <hip/hip_runtime.h>
#include <math.h>

namespace {

constexpr int E_  = 768;
constexpr int H_  = 12;
constexpr int DH_ = 64;
constexpr int T_  = 2048;
constexpr int B_  = 2;
constexpr int M_  = B_ * T_;  // 4096
constexpr int BH_ = B_ * H_;  // 24

typedef __attribute__((ext_vector_type(8))) short bf16x8;
typedef __attribute__((ext_vector_type(4))) float f32x4;

__device__ inline ushort f2bf(float f) {
  union { float f; unsigned u; } v; v.f = f;
  unsigned u = v.u + 0x7FFFu + ((v.u >> 16) & 1u);  // RNE
  return (ushort)(u >> 16);
}
__device__ inline float bf2f(ushort u) {
  union { unsigned u; float f; } v; v.u = (unsigned)u << 16; return v.f;
}

// async global->LDS, 16B per lane (wave-uniform LDS base, per-lane global src)
__device__ __forceinline__ void gl16(const ushort* g, ushort* l) {
  __builtin_amdgcn_global_load_lds(
      (const __attribute__((address_space(1))) unsigned int*)(g),
      (__attribute__((address_space(3))) unsigned int*)(l), 16, 0, 0);
}

// ---------------------------------------------------------------------------
// prep: blocks [0,1536) convert x f32->bf16; blocks [1536,2112) transpose W.
// ---------------------------------------------------------------------------
constexpr int NCONV = 1536;

__global__ __launch_bounds__(256) void prep_k(
    const float* __restrict__ x,
    const float* __restrict__ Wq, const float* __restrict__ Wk,
    const float* __restrict__ Wv, const float* __restrict__ Wp,
    ushort* __restrict__ xb, ushort* __restrict__ Wt, ushort* __restrict__ Wpt)
{
  __shared__ float tile[64][65];
  const int bid = blockIdx.x;
  const int tid = threadIdx.x;

  if (bid < NCONV) {
    const size_t i = ((size_t)bid * 256 + tid) * 8;
    float4 a = *(const float4*)(x + i);
    float4 b = *(const float4*)(x + i + 4);
    ushort o[8] = {f2bf(a.x), f2bf(a.y), f2bf(a.z), f2bf(a.w),
                   f2bf(b.x), f2bf(b.y), f2bf(b.z), f2bf(b.w)};
    *(bf16x8*)(xb + i) = *(bf16x8*)o;
    return;
  }

  const int wb = bid - NCONV;  // 0..575
  const int tr = tid >> 4, tc = tid & 15;
  const float* src; ushort* dst;
  int k0, n0, sN, dK;
  if (wb < 432) {
    const int mat = wb / 144, rem = wb % 144;
    const int h = rem / 12, ktile = rem % 12;
    const float* W = (mat == 0) ? Wq : (mat == 1) ? Wk : Wv;
    src = W + (size_t)h * E_ * DH_;
    dst = Wt + (size_t)(mat * H_ + h) * DH_ * E_;
    k0 = ktile * 64; n0 = 0; sN = DH_; dK = E_;
  } else {
    const int rem = wb - 432;
    src = Wp;
    dst = Wpt;
    k0 = (rem / 12) * 64; n0 = (rem % 12) * 64; sN = E_; dK = E_;
  }

#pragma unroll
  for (int rr = 0; rr < 64; rr += 16) {
    float4 v = *(const float4*)(src + (size_t)(k0 + tr + rr) * sN + n0 + tc * 4);
    tile[tr + rr][tc * 4 + 0] = v.x;
    tile[tr + rr][tc * 4 + 1] = v.y;
    tile[tr + rr][tc * 4 + 2] = v.z;
    tile[tr + rr][tc * 4 + 3] = v.w;
  }
  __syncthreads();
#pragma unroll
  for (int rr = 0; rr < 64; rr += 16) {
    const int n = tr + rr;
    ushort4 o;
    o.x = f2bf(tile[tc * 4 + 0][n]);
    o.y = f2bf(tile[tc * 4 + 1][n]);
    o.z = f2bf(tile[tc * 4 + 2][n]);
    o.w = f2bf(tile[tc * 4 + 3][n]);
    *(ushort4*)(dst + (size_t)(n0 + n) * dK + k0 + tc * 4) = o;
  }
}

// ---------------------------------------------------------------------------
// QKV GEMM: 128x64 tiles (grid 36x32 = 1152 blocks -> 4.5 blocks/CU).
// gload_lds staging, linear LDS + pre-swizzled source. One 64-col segment
// per block -> simple epilogue (Q scaled / K direct / V transpose-bounce).
// ---------------------------------------------------------------------------
constexpr float QSCALE = 0.18033688f;  // 1/8 * log2(e)

__global__ __launch_bounds__(256) void qkv_fused_k(
    const ushort* __restrict__ xb, const ushort* __restrict__ Wt,
    ushort* __restrict__ q_ws, ushort* __restrict__ k_ws, ushort* __restrict__ vt_ws)
{
  __shared__ __align__(16) ushort lds[(128 + 64) * 64];  // As | Bs (24 KB)
  ushort* As = lds;
  ushort* Bs = lds + 128 * 64;

  const int seg = blockIdx.x;        // 0..35: (mat, head)
  const int n0g = 0;                 // B row base within segment
  const int m0  = blockIdx.y * 128;
  const ushort* Wh = Wt + (size_t)seg * DH_ * E_;

  const int tid  = threadIdx.x;
  const int w    = tid >> 6, l = tid & 63;
  const int lrow = l & 15, lk = l >> 4;
  const int r7   = lrow & 7;
  const int srow = l >> 3;
  const int sch  = (l & 7) ^ srow;

  f32x4 acc[2][4] = {};

  for (int k0 = 0; k0 < E_; k0 += 64) {
#pragma unroll
    for (int r = 0; r < 4; ++r) {
      const int base = r * 32 + w * 8;
      gl16(xb + (size_t)(m0 + base + srow) * E_ + k0 + sch * 8, &As[base * 64]);
      if (r < 2)
        gl16(Wh + (size_t)(n0g + base + srow) * E_ + k0 + sch * 8, &Bs[base * 64]);
    }
    __syncthreads();

#pragma unroll
    for (int kk = 0; kk < 2; ++kk) {
      const int cof = ((kk * 4 + lk) ^ r7) * 8;
      const bf16x8 a0 = *(const bf16x8*)&As[(w * 32 + lrow) * 64 + cof];
      const bf16x8 a1 = *(const bf16x8*)&As[(w * 32 + 16 + lrow) * 64 + cof];
#pragma unroll
      for (int nf = 0; nf < 4; ++nf) {
        const bf16x8 b = *(const bf16x8*)&Bs[(nf * 16 + lrow) * 64 + cof];
        acc[0][nf] = __builtin_amdgcn_mfma_f32_16x16x32_bf16(a0, b, acc[0][nf], 0, 0, 0);
        acc[1][nf] = __builtin_amdgcn_mfma_f32_16x16x32_bf16(a1, b, acc[1][nf], 0, 0, 0);
      }
    }
    __syncthreads();
  }

  const int b   = m0 >> 11;
  const int t0  = m0 & 2047;
  const int mat = seg / H_;
  const int h   = seg - mat * H_;
  const int bh  = b * H_ + h;

  if (mat != 2) {
    const float qs = (mat == 0) ? QSCALE : 1.0f;
    ushort* outw = (mat == 0) ? q_ws : k_ws;
#pragma unroll
    for (int mi = 0; mi < 2; ++mi)
#pragma unroll
      for (int i = 0; i < 4; ++i) {
        const int t = t0 + w * 32 + mi * 16 + lk * 4 + i;
        ushort* orow = outw + ((size_t)bh * T_ + t) * DH_;
#pragma unroll
        for (int nf = 0; nf < 4; ++nf)
          orow[nf * 16 + lrow] = f2bf(acc[mi][nf][i] * qs);
      }
  } else {
    // V: transpose 128x64 tile via LDS bounce -> vt_ws[bh][d][t]
    ushort* Td = lds;  // [64][136] = 17 KB
    __syncthreads();
#pragma unroll
    for (int mi = 0; mi < 2; ++mi)
#pragma unroll
      for (int i = 0; i < 4; ++i) {
        const int tl = w * 32 + mi * 16 + lk * 4 + i;
#pragma unroll
        for (int nf = 0; nf < 4; ++nf)
          Td[(nf * 16 + lrow) * 136 + tl] = f2bf(acc[mi][nf][i]);
      }
    __syncthreads();
#pragma unroll
    for (int it = 0; it < 4; ++it) {
      const int c = tid + it * 256;
      const int d = c >> 4, sub = c & 15;
      *(bf16x8*)(vt_ws + ((size_t)bh * DH_ + d) * T_ + t0 + sub * 8) =
          *(const bf16x8*)&Td[d * 136 + sub * 8];
    }
  }
}

// ---------------------------------------------------------------------------
// Causal flash attention with k-range split x2 (unchanged from R8).
// ---------------------------------------------------------------------------
__global__ __launch_bounds__(256) void attn_split_k(
    const ushort* __restrict__ q_ws, const ushort* __restrict__ k_ws,
    const ushort* __restrict__ vt_ws, ushort* __restrict__ op_ws,
    float2* __restrict__ ml_ws)
{
  __shared__ __align__(16) ushort Ks[64 * 64];
  __shared__ __align__(16) ushort Vt[64 * 64];
  __shared__ __align__(16) ushort Pl[4][16 * 64];

  const int qt = 31 - (int)blockIdx.y;
  const int bh = blockIdx.x;
  const int hz = blockIdx.z;
  const int nt = qt + 1;
  const int klo = hz ? (nt >> 1) : 0;
  const int khi = hz ? nt : (nt >> 1);
  const int q0 = qt * 64;

  const ushort* Qb  = q_ws + (size_t)bh * T_ * DH_;
  const ushort* Kb  = k_ws + (size_t)bh * T_ * DH_;
  const ushort* VTb = vt_ws + (size_t)bh * DH_ * T_;

  const int tid  = threadIdx.x;
  const int w    = tid >> 6;
  const int l    = tid & 63;
  const int lrow = l & 15;
  const int lk   = l >> 4;
  const int r7   = lrow & 7;
  const int rr   = tid >> 3;
  const int sub  = tid & 7;
  const int swc  = sub ^ (rr & 7);

  const int st0 = rr * 64 + swc * 8;
  const int st1 = (rr + 32) * 64 + swc * 8;

  int kof0[4], kof1[4];
#pragma unroll
  for (int ct = 0; ct < 4; ++ct) {
    kof0[ct] = (ct * 16 + lrow) * 64 + ((lk ^ r7) * 8);
    kof1[ct] = (ct * 16 + lrow) * 64 + (((lk + 4) ^ r7) * 8);
  }

  const ushort* Qrow = Qb + (size_t)(q0 + w * 16 + lrow) * DH_;
  const bf16x8 qa0 = *(const bf16x8*)(Qrow + lk * 8);
  const bf16x8 qa1 = *(const bf16x8*)(Qrow + lk * 8 + 32);
  const int qglob = q0 + w * 16 + lrow;

  float m_r = -INFINITY, l_r = 0.f;
  f32x4 oc[4] = {};

  ushort* Pw = &Pl[w][0];
  const int rd0 = lrow * 64 + ((lk ^ r7) * 8);
  const int rd1 = lrow * 64 + (((lk + 4) ^ r7) * 8);
  const int wrbase  = lrow * 128 + (lk & 1) * 8;
  const int wrchunk = (lk >> 1);

  if (klo < khi) {
    bf16x8 kp0 = *(const bf16x8*)(Kb + (size_t)(klo * 64 + rr) * DH_ + sub * 8);
    bf16x8 kp1 = *(const bf16x8*)(Kb + (size_t)(klo * 64 + rr + 32) * DH_ + sub * 8);
    bf16x8 vp0 = *(const bf16x8*)(VTb + (size_t)rr * T_ + klo * 64 + sub * 8);
    bf16x8 vp1 = *(const bf16x8*)(VTb + (size_t)(rr + 32) * T_ + klo * 64 + sub * 8);

    for (int kt = klo; kt < khi; ++kt) {
      const int s0 = kt * 64;

      *(bf16x8*)&Ks[st0] = kp0;
      *(bf16x8*)&Ks[st1] = kp1;
      *(bf16x8*)&Vt[st0] = vp0;
      *(bf16x8*)&Vt[st1] = vp1;
      __syncthreads();

      if (kt + 1 < khi) {
        const int sn = s0 + 64;
        kp0 = *(const bf16x8*)(Kb + (size_t)(sn + rr) * DH_ + sub * 8);
        kp1 = *(const bf16x8*)(Kb + (size_t)(sn + rr + 32) * DH_ + sub * 8);
        vp0 = *(const bf16x8*)(VTb + (size_t)rr * T_ + sn + sub * 8);
        vp1 = *(const bf16x8*)(VTb + (size_t)(rr + 32) * T_ + sn + sub * 8);
      }

      f32x4 st[4];
#pragma unroll
      for (int ct = 0; ct < 4; ++ct) {
        const bf16x8 kb0 = *(const bf16x8*)&Ks[kof0[ct]];
        const bf16x8 kb1 = *(const bf16x8*)&Ks[kof1[ct]];
        f32x4 z = {0.f, 0.f, 0.f, 0.f};
        z = __builtin_amdgcn_mfma_f32_16x16x32_bf16(kb0, qa0, z, 0, 0, 0);
        st[ct] = __builtin_amdgcn_mfma_f32_16x16x32_bf16(kb1, qa1, z, 0, 0, 0);
      }

      if (kt == qt) {
#pragma unroll
        for (int ct = 0; ct < 4; ++ct)
#pragma unroll
          for (int i = 0; i < 4; ++i)
            if (s0 + ct * 16 + lk * 4 + i > qglob) st[ct][i] = -INFINITY;
      }

      float mc[4];
#pragma unroll
      for (int ct = 0; ct < 4; ++ct)
        mc[ct] = fmaxf(fmaxf(st[ct][0], st[ct][1]), fmaxf(st[ct][2], st[ct][3]));
      float mx = fmaxf(fmaxf(mc[0], mc[1]), fmaxf(mc[2], mc[3]));
      mx = fmaxf(mx, __shfl_xor(mx, 16));
      mx = fmaxf(mx, __shfl_xor(mx, 32));

      if (__any(mx > m_r + 8.f)) {
        const float mn   = fmaxf(m_r, mx);
        const float corr = exp2f(m_r - mn);
        m_r = mn;
        l_r *= corr;
#pragma unroll
        for (int i = 0; i < 4; ++i) {
          const float cr = __shfl(corr, lk * 4 + i);
#pragma unroll
          for (int ct = 0; ct < 4; ++ct) oc[ct][i] *= cr;
        }
      }

      float sc[4];
#pragma unroll
      for (int ct = 0; ct < 4; ++ct) {
#pragma unroll
        for (int i = 0; i < 4; ++i) st[ct][i] = exp2f(st[ct][i] - m_r);
        sc[ct] = (st[ct][0] + st[ct][1]) + (st[ct][2] + st[ct][3]);
      }
      float rs = (sc[0] + sc[1]) + (sc[2] + sc[3]);
      rs += __shfl_xor(rs, 16);
      rs += __shfl_xor(rs, 32);
      l_r += rs;

#pragma unroll
      for (int ct = 0; ct < 4; ++ct) {
        unsigned lo, hi;
        asm("v_cvt_pk_bf16_f32 %0, %1, %2" : "=v"(lo) : "v"(st[ct][0]), "v"(st[ct][1]));
        asm("v_cvt_pk_bf16_f32 %0, %1, %2" : "=v"(hi) : "v"(st[ct][2]), "v"(st[ct][3]));
        uint2 pk; pk.x = lo; pk.y = hi;
        const int ch = ((ct * 2 + wrchunk) ^ r7);
        *(uint2*)((char*)Pw + wrbase + ch * 16) = pk;
      }

      const bf16x8 pa0 = *(const bf16x8*)(Pw + rd0);
      const bf16x8 pa1 = *(const bf16x8*)(Pw + rd1);

#pragma unroll
      for (int ct = 0; ct < 4; ++ct) {
        const bf16x8 vb0 = *(const bf16x8*)&Vt[kof0[ct]];
        const bf16x8 vb1 = *(const bf16x8*)&Vt[kof1[ct]];
        oc[ct] = __builtin_amdgcn_mfma_f32_16x16x32_bf16(pa0, vb0, oc[ct], 0, 0, 0);
        oc[ct] = __builtin_amdgcn_mfma_f32_16x16x32_bf16(pa1, vb1, oc[ct], 0, 0, 0);
      }
      __syncthreads();
    }
  }

  const size_t pb = (size_t)(hz * BH_ + bh) * T_;
  if (lk == 0)
    ml_ws[pb + q0 + w * 16 + lrow] = make_float2(m_r, l_r);
#pragma unroll
  for (int i = 0; i < 4; ++i) {
    const int t = q0 + w * 16 + lk * 4 + i;
    ushort* orow = op_ws + (pb + t) * DH_;
#pragma unroll
    for (int ct = 0; ct < 4; ++ct)
      orow[ct * 16 + lrow] = f2bf(oc[ct][i]);
  }
}

// ---------------------------------------------------------------------------
// Out-proj GEMM with FUSED split-k combine: 64x64 tiles (grid 12x64 = 768
// blocks -> 3/CU). A-tile rows are (b,t), its 64 k-columns are exactly one
// head h = k0/64 -> combine weights are per-row; A is reg-staged with the
// combine applied, ds_written swizzled. B via gload_lds.
// ---------------------------------------------------------------------------
__global__ __launch_bounds__(256) void proj_fused_k(
    const ushort* __restrict__ op_ws, const float2* __restrict__ ml_ws,
    const ushort* __restrict__ Wpt, const float* __restrict__ bp,
    float* __restrict__ out)
{
  __shared__ __align__(16) ushort lds[(64 + 64) * 64];  // As | Bs (16 KB)
  ushort* As = lds;
  ushort* Bs = lds + 64 * 64;

  const int n0 = blockIdx.x * 64;
  const int m0 = blockIdx.y * 64;
  const int b  = m0 >> 11;
  const int t0 = m0 & 2047;

  const int tid  = threadIdx.x;
  const int w    = tid >> 6, l = tid & 63;
  const int lrow = l & 15, lk = l >> 4;
  const int r7   = lrow & 7;
  const int srow = l >> 3;
  const int sch  = (l & 7) ^ srow;
  // A combine-staging layout: thread covers row ar, 16-elem chunk cc
  const int ar = tid >> 2;          // 0..63
  const int cc = tid & 3;           // 0..3
  const int a7 = ar & 7;

  f32x4 acc[4] = {};

  for (int k0 = 0; k0 < E_; k0 += 64) {
    const int h  = k0 >> 6;
    const int bh = b * H_ + h;

    // B staging (async)
#pragma unroll
    for (int r = 0; r < 2; ++r) {
      const int base = r * 32 + w * 8;
      gl16(Wpt + (size_t)(n0 + base + srow) * E_ + k0 + sch * 8, &Bs[base * 64]);
    }

    // A staging: combine two k-half partials in regs, swizzled ds_write
    {
      const int t = t0 + ar;
      const size_t ixA = (size_t)bh * T_ + t;
      const size_t ixB = (size_t)(BH_ + bh) * T_ + t;
      const float2 mlA = ml_ws[ixA];
      const float2 mlB = ml_ws[ixB];
      const float m   = fmaxf(mlA.x, mlB.x);
      const float wA  = exp2f(mlA.x - m);
      const float wB  = exp2f(mlB.x - m);
      const float inv = 1.0f / (wA * mlA.y + wB * mlB.y);
      const float fA = wA * inv, fB = wB * inv;

      const ushort* pA = op_ws + ixA * DH_ + cc * 16;
      const ushort* pB = op_ws + ixB * DH_ + cc * 16;
      bf16x8 a0 = *(const bf16x8*)pA;
      bf16x8 a1 = *(const bf16x8*)(pA + 8);
      bf16x8 b0 = *(const bf16x8*)pB;
      bf16x8 b1 = *(const bf16x8*)(pB + 8);
      ushort o[16];
#pragma unroll
      for (int j = 0; j < 8; ++j) {
        o[j]     = f2bf(fA * bf2f((ushort)a0[j]) + fB * bf2f((ushort)b0[j]));
        o[8 + j] = f2bf(fA * bf2f((ushort)a1[j]) + fB * bf2f((ushort)b1[j]));
      }
      *(bf16x8*)&As[ar * 64 + ((2 * cc) ^ a7) * 8]     = *(const bf16x8*)&o[0];
      *(bf16x8*)&As[ar * 64 + ((2 * cc + 1) ^ a7) * 8] = *(const bf16x8*)&o[8];
    }
    __syncthreads();

#pragma unroll
    for (int kk = 0; kk < 2; ++kk) {
      const int cof = ((kk * 4 + lk) ^ r7) * 8;
      const bf16x8 a = *(const bf16x8*)&As[(w * 16 + lrow) * 64 + cof];
#pragma unroll
      for (int nf = 0; nf < 4; ++nf) {
        const bf16x8 bb = *(const bf16x8*)&Bs[(nf * 16 + lrow) * 64 + cof];
        acc[nf] = __builtin_amdgcn_mfma_f32_16x16x32_bf16(a, bb, acc[nf], 0, 0, 0);
      }
    }
    __syncthreads();
  }

  float bias[4];
#pragma unroll
  for (int nf = 0; nf < 4; ++nf) bias[nf] = bp[n0 + nf * 16 + lrow];

#pragma unroll
  for (int i = 0; i < 4; ++i) {
    const int m = m0 + w * 16 + lk * 4 + i;
    float* orow = out + (size_t)m * E_ + n0;
#pragma unroll
    for (int nf = 0; nf < 4; ++nf)
      orow[nf * 16 + lrow] = acc[nf][i] + bias[nf];
  }
}

}  // namespace

extern "C" void kernel_launch(void* const* d_in, const int* in_sizes, int n_in,
                              void* d_out, int out_size, void* d_ws, size_t ws_size,
                              hipStream_t stream) {
  const float* x  = (const float*)d_in[0];
  const float* Wq = (const float*)d_in[1];
  const float* Wk = (const float*)d_in[2];
  const float* Wv = (const float*)d_in[3];
  const float* Wp = (const float*)d_in[4];
  const float* bp = (const float*)d_in[5];
  float* out = (float*)d_out;

  const size_t nx  = (size_t)M_ * E_;            // 3,145,728
  const size_t nwt = (size_t)3 * H_ * DH_ * E_;  // 1,769,472
  const size_t nwp = (size_t)E_ * E_;            // 589,824
  const size_t per = (size_t)BH_ * T_ * DH_;     // 3,145,728

  ushort* xb    = (ushort*)d_ws;
  ushort* Wt    = xb + nx;
  ushort* Wpt   = Wt + nwt;
  ushort* q_ws  = Wpt + nwp;
  ushort* k_ws  = q_ws + per;
  ushort* vt_ws = k_ws + per;     // [bh][d][t]
  ushort* op_ws = vt_ws + per;    // [2][bh][t][64] partials
  float2* ml_ws = (float2*)(op_ws + 2 * per);  // [2][bh][t]

  prep_k<<<dim3(NCONV + 576), 256, 0, stream>>>(x, Wq, Wk, Wv, Wp, xb, Wt, Wpt);
  qkv_fused_k<<<dim3(36, 32), 256, 0, stream>>>(xb, Wt, q_ws, k_ws, vt_ws);
  attn_split_k<<<dim3(24, 32, 2), 256, 0, stream>>>(q_ws, k_ws, vt_ws, op_ws, ml_ws);
  proj_fused_k<<<dim3(12, 64), 256, 0, stream>>>(op_ws, ml_ws, Wpt, bp, out);
}